// Round 3
// baseline (224.004 us; speedup 1.0000x reference)
//
#include <hip/hip_runtime.h>

#define K_SEL 103
#define TWO_PI 6.283185307179586f
typedef unsigned short ushort_t;
typedef unsigned long long ull_t;

__device__ inline ushort_t f2bf(float f) {
    unsigned u = __float_as_uint(f);
    unsigned r = u + 0x7fffu + ((u >> 16) & 1u);   // RNE
    return (ushort_t)(r >> 16);
}

// ---------------- K1: xl = x @ W_lin^T + b_lin  (16384 x 64), + W2t build ---
__global__ __launch_bounds__(256) void k1_lin(const float* __restrict__ x,
                                              const float* __restrict__ W,
                                              const float* __restrict__ b,
                                              float* __restrict__ xl,
                                              const float* __restrict__ W2,
                                              const float* __restrict__ filt,
                                              float* __restrict__ W2t) {
    // fold former k0: 1024 blocks x 66 = 67584 = 2112*32 exactly
    if (threadIdx.x < 66) {
        int t = blockIdx.x * 66 + threadIdx.x;
        int d = t & 31;
        int e = t >> 5;
        int c = e & 63;
        int j = e >> 6;
        W2t[t] = (j < 32) ? W2[(c * 32 + d) * 32 + j] : filt[c * 32 + d];
    }
    __shared__ float Wt[64 * 64];   // Wt[j*64+i] = W[i*64+j]
    for (int t = threadIdx.x; t < 4096; t += 256)
        Wt[(t & 63) * 64 + (t >> 6)] = W[t];
    __syncthreads();
    int i = threadIdx.x & 63;
    int sub = threadIdx.x >> 6;
    int r0 = blockIdx.x * 16 + sub * 4;
    float bi = b[i];
    float acc0 = bi, acc1 = bi, acc2 = bi, acc3 = bi;
    const float* xr = x + (size_t)r0 * 64;
    #pragma unroll 4
    for (int jj = 0; jj < 16; ++jj) {
        float4 v0 = *(const float4*)(xr + 0 * 64 + jj * 4);
        float4 v1 = *(const float4*)(xr + 1 * 64 + jj * 4);
        float4 v2 = *(const float4*)(xr + 2 * 64 + jj * 4);
        float4 v3 = *(const float4*)(xr + 3 * 64 + jj * 4);
        float w0 = Wt[(jj * 4 + 0) * 64 + i];
        float w1 = Wt[(jj * 4 + 1) * 64 + i];
        float w2 = Wt[(jj * 4 + 2) * 64 + i];
        float w3 = Wt[(jj * 4 + 3) * 64 + i];
        acc0 += v0.x * w0 + v0.y * w1 + v0.z * w2 + v0.w * w3;
        acc1 += v1.x * w0 + v1.y * w1 + v1.z * w2 + v1.w * w3;
        acc2 += v2.x * w0 + v2.y * w1 + v2.z * w2 + v2.w * w3;
        acc3 += v3.x * w0 + v3.y * w1 + v3.z * w2 + v3.w * w3;
    }
    xl[(size_t)(r0 + 0) * 64 + i] = acc0;
    xl[(size_t)(r0 + 1) * 64 + i] = acc1;
    xl[(size_t)(r0 + 2) * 64 + i] = acc2;
    xl[(size_t)(r0 + 3) * 64 + i] = acc3;
}

// ---------------- K2: per-query neighbor select (histogram) + kernel-MLP ----
// bin(e) = floor(e*8192) is exact (x2^13) and monotone; boundary bin resolved
// exactly by (ebits,idx) sort -> matches top_k tie-break. Slot order arbitrary
// (downstream is order-invariant over k).
__global__ __launch_bounds__(256) void k2_select(const float* __restrict__ pos,
                                                 const float* __restrict__ qpos,
                                                 const float* __restrict__ Bmat,
                                                 const float* __restrict__ W1,
                                                 const float* __restrict__ b1,
                                                 float* __restrict__ Hg,
                                                 int* __restrict__ indg) {
    const int q = blockIdx.x;
    const int tid = threadIdx.x;
    const int lane = tid & 63;
    const int wid = tid >> 6;

    __shared__ unsigned ebits[2048];
    __shared__ unsigned hist[4096];
    __shared__ float W1s[1024];
    __shared__ float b1s[32];
    __shared__ float Bm[32];
    __shared__ float sred[256];
    __shared__ int   sel_v[K_SEL];
    __shared__ float sel_e[K_SEL];     // later reused to hold w
    __shared__ ull_t bnd[128];
    __shared__ int   counters[2];      // slot(less), nBnd
    __shared__ int   info[2];          // Bstar, L
    __shared__ unsigned wsum[4];
    __shared__ float emax_s;

    for (int t = tid; t < 1024; t += 256) W1s[t] = W1[t];
    if (tid < 32) { b1s[tid] = b1[tid]; Bm[tid] = Bmat[tid]; }
    if (tid < 2)  counters[tid] = 0;
    for (int t = tid; t < 4096; t += 256) hist[t] = 0;

    const float qp0 = qpos[q * 2 + 0];
    const float qp1 = qpos[q * 2 + 1];
    __syncthreads();

    float lmin = 1e30f;
    for (int v = tid; v < 2048; v += 256) {
        float d0 = qp0 - pos[v * 2 + 0];
        float d1 = qp1 - pos[v * 2 + 1];
        d0 += 0.5f; d0 -= floorf(d0); d0 -= 0.5f;
        d1 += 0.5f; d1 -= floorf(d1); d1 -= 0.5f;
        float e = d0 * d0 + d1 * d1;
        ebits[v] = __float_as_uint(e);
        lmin = fminf(lmin, e);
        int bb = (int)(e * 8192.0f); bb = (bb > 4095) ? 4095 : bb;
        atomicAdd(&hist[bb], 1u);
    }
    sred[tid] = lmin;
    __syncthreads();
    for (int s = 128; s > 0; s >>= 1) {
        if (tid < s) sred[tid] = fminf(sred[tid], sred[tid + s]);
        __syncthreads();
    }
    const float e_min = sred[0];
    __syncthreads();

    // ---- scan of 4096-bin histogram (16 bins/thread + shuffle scan)
    unsigned lsum = 0;
    #pragma unroll
    for (int i = 0; i < 16; ++i) lsum += hist[tid * 16 + i];
    unsigned vq = lsum;
    #pragma unroll
    for (int off = 1; off < 64; off <<= 1) {
        unsigned n = __shfl_up(vq, off, 64);
        if (lane >= off) vq += n;
    }
    if (lane == 63) wsum[wid] = vq;
    __syncthreads();
    unsigned base = 0;
    for (int w2 = 0; w2 < wid; ++w2) base += wsum[w2];
    unsigned cum = base + vq - lsum;       // exclusive prefix of this 16-bin group
    #pragma unroll
    for (int i = 0; i < 16; ++i) {
        unsigned cnt = hist[tid * 16 + i];
        if (cum <= 102u && 102u < cum + cnt) { info[0] = tid * 16 + i; info[1] = (int)cum; }
        cum += cnt;
    }
    __syncthreads();
    const int Bstar = info[0];
    const int L = info[1];
    const int need = K_SEL - L;            // >= 1, <= count(Bstar)

    // ---- compaction
    for (int v = tid; v < 2048; v += 256) {
        unsigned bb = ebits[v];
        float e = __uint_as_float(bb);
        int bin = (int)(e * 8192.0f); bin = (bin > 4095) ? 4095 : bin;
        if (bin < Bstar) {
            int s2 = atomicAdd(&counters[0], 1);
            sel_v[s2] = v; sel_e[s2] = e;
        } else if (bin == Bstar) {
            int s2 = atomicAdd(&counters[1], 1);
            if (s2 < 128) bnd[s2] = (((ull_t)bb) << 32) | (unsigned)v;
        }
    }
    __syncthreads();
    if (tid == 0) {
        int nb = counters[1]; if (nb > 128) nb = 128;
        for (int i = 1; i < nb; ++i) {       // tiny sort by (ebits, idx) asc
            ull_t key = bnd[i]; int j2 = i - 1;
            while (j2 >= 0 && bnd[j2] > key) { bnd[j2 + 1] = bnd[j2]; --j2; }
            bnd[j2 + 1] = key;
        }
        for (int i = 0; i < need; ++i) {
            sel_v[L + i] = (int)(unsigned)(bnd[i] & 0xffffffffull);
            sel_e[L + i] = __uint_as_float((unsigned)(bnd[i] >> 32));
        }
        emax_s = __uint_as_float((unsigned)(bnd[need - 1] >> 32));  // rank-102
    }
    __syncthreads();

    const float denom = (emax_s - e_min) + 1e-8f;
    float w = 0.0f;
    if (tid < K_SEL) w = __expf(-(sel_e[tid] - e_min) / denom);
    if (tid < K_SEL) sel_e[tid] = w;       // own-slot overwrite
    if (tid < 128) sred[tid] = (tid < K_SEL) ? w : 0.0f;
    __syncthreads();
    for (int s = 64; s > 0; s >>= 1) {
        if (tid < s) sred[tid] += sred[tid + s];
        __syncthreads();
    }
    const float total = sred[0];

    // ---- RFF + MLP: 2 threads per k, v_sin/v_cos in revolutions
    if (tid < 2 * K_SEL) {
        const int k = tid >> 1;
        const int io = (tid & 1) * 16;
        const int v = sel_v[k];
        const float kd = sel_e[k] / total;
        float d0 = qp0 - pos[v * 2 + 0];
        float d1 = qp1 - pos[v * 2 + 1];
        d0 += 0.5f; d0 -= floorf(d0); d0 -= 0.5f;
        d1 += 0.5f; d1 -= floorf(d1); d1 -= 0.5f;
        float kf[32];
        #pragma unroll
        for (int f = 0; f < 16; ++f) {
            float t = d0 * Bm[f] + d1 * Bm[16 + f];   // revolutions
            float r = t - rintf(t);                   // [-0.5, 0.5]
            kf[f]      = __builtin_amdgcn_sinf(r);    // sin(2*pi*r)
            kf[16 + f] = __builtin_amdgcn_cosf(r);
        }
        float* hout = Hg + ((size_t)q * K_SEL + k) * 36;
        #pragma unroll 4
        for (int i = io; i < io + 16; ++i) {
            float pre = b1s[i];
            #pragma unroll
            for (int jf = 0; jf < 32; ++jf) pre += kf[jf] * W1s[i * 32 + jf];
            float g = 0.5f * pre * (1.0f + erff(pre * 0.70710678118654752f));
            hout[i] = g * kd;
        }
        if ((tid & 1) == 0) {
            hout[32] = kd;
            indg[q * K_SEL + k] = v;
        }
    }
}

// ---------------- K3: fused per (q, bt-half): GEMM1 + GEMM2 -----------------
// Block handles q = bid>>1, bts = (bid&1)*4 .. +3.
// GEMM1: Z[j,c] = sum_k H[k,j]*xl[bt,ind[k],c]  (direct global reads, balanced:
//        thread=(j<32, 8 c's)); row j=32 (kd) via separate phase (bt,c)/thread.
// Zs bf16 [e][4bt]; GEMM2: one W2t pass, 16 accum/thread, LDS reduce over eg.
__global__ __launch_bounds__(256, 4) void k3_main(const float* __restrict__ xl,
                                                  const float* __restrict__ Hg,
                                                  const int* __restrict__ indg,
                                                  const float* __restrict__ W2t,
                                                  const float* __restrict__ bias,
                                                  float* __restrict__ out) {
    const int bid = blockIdx.x;
    const int q = bid >> 1;
    const int bt0 = (bid & 1) * 4;
    const int tid = threadIdx.x;

    __shared__ float smem[7932];       // Hs(3708) | Zs-bf16(2112*4) = 31.7 KB
    __shared__ int ind_s[K_SEL];
    float* Hs = smem;                              // 103*36 fp32
    ushort_t* Zs = (ushort_t*)(smem + 3708);       // [e][bt] bf16, e<2112
    float* red = smem + 3708;                      // alias Zs: 32*128 fp32

    const float* hgq = Hg + (size_t)q * (K_SEL * 36);
    for (int t = tid; t < K_SEL * 36; t += 256) Hs[t] = hgq[t];
    for (int t = tid; t < K_SEL; t += 256) ind_s[t] = indg[q * K_SEL + t] << 6;
    __syncthreads();

    // ---- GEMM1 (balanced): thread = (j = tid>>3 in [0,32), c0 = (tid&7)*8)
    const int j = tid >> 3;
    const int c0 = (tid & 7) * 8;
    float acc[4][8];
    #pragma unroll
    for (int bt = 0; bt < 4; ++bt)
        #pragma unroll
        for (int i = 0; i < 8; ++i) acc[bt][i] = 0.0f;

    #pragma unroll
    for (int bt = 0; bt < 4; ++bt) {
        const float* xb = xl + (size_t)(bt0 + bt) * 131072 + c0;
        for (int k = 0; k < K_SEL; ++k) {
            int off = ind_s[k];
            float4 xa = *(const float4*)(xb + off);
            float4 xc = *(const float4*)(xb + off + 4);
            float h = Hs[k * 36 + j];
            acc[bt][0] += h * xa.x; acc[bt][1] += h * xa.y;
            acc[bt][2] += h * xa.z; acc[bt][3] += h * xa.w;
            acc[bt][4] += h * xc.x; acc[bt][5] += h * xc.y;
            acc[bt][6] += h * xc.z; acc[bt][7] += h * xc.w;
        }
    }
    // store Zs rows e = j*64 + c0 + cc, packed over 4 bt
    #pragma unroll
    for (int cc = 0; cc < 8; ++cc) {
        int e = j * 64 + c0 + cc;
        unsigned p0 = (unsigned)f2bf(acc[0][cc]) | ((unsigned)f2bf(acc[1][cc]) << 16);
        unsigned p1 = (unsigned)f2bf(acc[2][cc]) | ((unsigned)f2bf(acc[3][cc]) << 16);
        *(uint2*)(&Zs[e * 4]) = make_uint2(p0, p1);
    }
    // ---- filt row (j=32): s[bt,c] = sum_k kd[k]*xl[bt,ind[k],c]
    {
        const int cph = tid & 63;
        const int btph = tid >> 6;
        const float* xbp = xl + (size_t)(bt0 + btph) * 131072 + cph;
        float sacc = 0.0f;
        for (int k = 0; k < K_SEL; ++k)
            sacc += Hs[k * 36 + 32] * xbp[ind_s[k]];
        Zs[(2048 + cph) * 4 + btph] = f2bf(sacc);
    }
    __syncthreads();

    // ---- GEMM2: one W2t pass; thread = (eg = tid>>3, d0 = (tid&7)*4)
    const int eg = tid >> 3;
    const int d0v = (tid & 7) * 4;
    float oa[4][4];
    #pragma unroll
    for (int bt = 0; bt < 4; ++bt)
        #pragma unroll
        for (int i = 0; i < 4; ++i) oa[bt][i] = 0.0f;

    for (int ii = 0; ii < 66; ++ii) {
        int e = ii * 32 + eg;
        float4 w = *(const float4*)(W2t + (size_t)e * 32 + d0v);
        uint2 zp = *(const uint2*)(&Zs[e * 4]);
        float z0 = __uint_as_float(zp.x << 16);
        float z1 = __uint_as_float(zp.x & 0xffff0000u);
        float z2 = __uint_as_float(zp.y << 16);
        float z3 = __uint_as_float(zp.y & 0xffff0000u);
        oa[0][0] += z0 * w.x; oa[0][1] += z0 * w.y; oa[0][2] += z0 * w.z; oa[0][3] += z0 * w.w;
        oa[1][0] += z1 * w.x; oa[1][1] += z1 * w.y; oa[1][2] += z1 * w.z; oa[1][3] += z1 * w.w;
        oa[2][0] += z2 * w.x; oa[2][1] += z2 * w.y; oa[2][2] += z2 * w.z; oa[2][3] += z2 * w.w;
        oa[3][0] += z3 * w.x; oa[3][1] += z3 * w.y; oa[3][2] += z3 * w.z; oa[3][3] += z3 * w.w;
    }
    __syncthreads();   // all Zs reads done; red aliases Zs
    #pragma unroll
    for (int bt = 0; bt < 4; ++bt)
        #pragma unroll
        for (int i = 0; i < 4; ++i)
            red[eg * 128 + bt * 32 + d0v + i] = oa[bt][i];
    __syncthreads();
    if (tid < 128) {
        const int bt = tid >> 5;
        const int d = tid & 31;
        float s = bias[d];
        #pragma unroll
        for (int p = 0; p < 32; ++p) s += red[p * 128 + tid];
        out[((size_t)(bt0 + bt) * 512 + q) * 32 + d] = s;
    }
}

// ---------------------------------------------------------------------------
extern "C" void kernel_launch(void* const* d_in, const int* in_sizes, int n_in,
                              void* d_out, int out_size, void* d_ws, size_t ws_size,
                              hipStream_t stream) {
    const float* x     = (const float*)d_in[0];   // (2,4,2048,64)
    const float* pos   = (const float*)d_in[1];   // (2048,2)
    const float* qpos  = (const float*)d_in[2];   // (512,2)
    const float* W_lin = (const float*)d_in[3];   // (64,64)
    const float* b_lin = (const float*)d_in[4];   // (64)
    const float* Bmat  = (const float*)d_in[5];   // (2,16)
    const float* W1    = (const float*)d_in[6];   // (32,32)
    const float* b1    = (const float*)d_in[7];   // (32)
    const float* W2    = (const float*)d_in[8];   // (2048,32)
    const float* filt  = (const float*)d_in[9];   // (2048)
    const float* bias  = (const float*)d_in[10];  // (32)
    float* out = (float*)d_out;

    float* ws   = (float*)d_ws;
    float* xl   = ws;                      // 16384*64    = 1048576 floats
    float* Hg   = ws + 1048576;            // 512*103*36  = 1898496 floats
    int*   indg = (int*)(ws + 2947072);    // 512*103     = 52736 ints
    float* W2t  = ws + 2999808;            // 2112*32     = 67584 floats

    k1_lin<<<1024, 256, 0, stream>>>(x, W_lin, b_lin, xl, W2, filt, W2t);
    k2_select<<<512, 256, 0, stream>>>(pos, qpos, Bmat, W1, b1, Hg, indg);
    k3_main<<<1024, 256, 0, stream>>>(xl, Hg, indg, W2t, bias, out);
}

// Round 4
// 188.788 us; speedup vs baseline: 1.1865x; 1.1865x over previous
//
#include <hip/hip_runtime.h>

#define K_SEL 103
#define TWO_PI 6.283185307179586f
typedef unsigned short ushort_t;
typedef unsigned long long ull_t;
typedef _Float16 half8 __attribute__((ext_vector_type(8)));

__device__ inline ushort_t f2bf(float f) {
    unsigned u = __float_as_uint(f);
    unsigned r = u + 0x7fffu + ((u >> 16) & 1u);   // RNE
    return (ushort_t)(r >> 16);
}

// ---------------- K1: xlh = fp16(x @ W_lin^T + b_lin), + W2t build ----------
__global__ __launch_bounds__(256) void k1_lin(const float* __restrict__ x,
                                              const float* __restrict__ W,
                                              const float* __restrict__ b,
                                              _Float16* __restrict__ xlh,
                                              const float* __restrict__ W2,
                                              const float* __restrict__ filt,
                                              float* __restrict__ W2t) {
    // fold former k0: 1024 blocks x 66 = 67584 = 2112*32 exactly
    if (threadIdx.x < 66) {
        int t = blockIdx.x * 66 + threadIdx.x;
        int d = t & 31;
        int e = t >> 5;
        int c = e & 63;
        int j = e >> 6;
        W2t[t] = (j < 32) ? W2[(c * 32 + d) * 32 + j] : filt[c * 32 + d];
    }
    __shared__ float Wt[64 * 64];   // Wt[j*64+i] = W[i*64+j]
    for (int t = threadIdx.x; t < 4096; t += 256)
        Wt[(t & 63) * 64 + (t >> 6)] = W[t];
    __syncthreads();
    int i = threadIdx.x & 63;
    int sub = threadIdx.x >> 6;
    int r0 = blockIdx.x * 16 + sub * 4;
    float bi = b[i];
    float acc0 = bi, acc1 = bi, acc2 = bi, acc3 = bi;
    const float* xr = x + (size_t)r0 * 64;
    #pragma unroll 4
    for (int jj = 0; jj < 16; ++jj) {
        float4 v0 = *(const float4*)(xr + 0 * 64 + jj * 4);
        float4 v1 = *(const float4*)(xr + 1 * 64 + jj * 4);
        float4 v2 = *(const float4*)(xr + 2 * 64 + jj * 4);
        float4 v3 = *(const float4*)(xr + 3 * 64 + jj * 4);
        float w0 = Wt[(jj * 4 + 0) * 64 + i];
        float w1 = Wt[(jj * 4 + 1) * 64 + i];
        float w2 = Wt[(jj * 4 + 2) * 64 + i];
        float w3 = Wt[(jj * 4 + 3) * 64 + i];
        acc0 += v0.x * w0 + v0.y * w1 + v0.z * w2 + v0.w * w3;
        acc1 += v1.x * w0 + v1.y * w1 + v1.z * w2 + v1.w * w3;
        acc2 += v2.x * w0 + v2.y * w1 + v2.z * w2 + v2.w * w3;
        acc3 += v3.x * w0 + v3.y * w1 + v3.z * w2 + v3.w * w3;
    }
    xlh[(size_t)(r0 + 0) * 64 + i] = (_Float16)acc0;
    xlh[(size_t)(r0 + 1) * 64 + i] = (_Float16)acc1;
    xlh[(size_t)(r0 + 2) * 64 + i] = (_Float16)acc2;
    xlh[(size_t)(r0 + 3) * 64 + i] = (_Float16)acc3;
}

// ---------------- K2: per-query neighbor select (histogram) + kernel-MLP ----
// (unchanged from round 3 — isolating the k3 experiment; k2 counters next)
__global__ __launch_bounds__(256) void k2_select(const float* __restrict__ pos,
                                                 const float* __restrict__ qpos,
                                                 const float* __restrict__ Bmat,
                                                 const float* __restrict__ W1,
                                                 const float* __restrict__ b1,
                                                 float* __restrict__ Hg,
                                                 int* __restrict__ indg) {
    const int q = blockIdx.x;
    const int tid = threadIdx.x;
    const int lane = tid & 63;
    const int wid = tid >> 6;

    __shared__ unsigned ebits[2048];
    __shared__ unsigned hist[4096];
    __shared__ float W1s[1024];
    __shared__ float b1s[32];
    __shared__ float Bm[32];
    __shared__ float sred[256];
    __shared__ int   sel_v[K_SEL];
    __shared__ float sel_e[K_SEL];
    __shared__ ull_t bnd[128];
    __shared__ int   counters[2];
    __shared__ int   info[2];
    __shared__ unsigned wsum[4];
    __shared__ float emax_s;

    for (int t = tid; t < 1024; t += 256) W1s[t] = W1[t];
    if (tid < 32) { b1s[tid] = b1[tid]; Bm[tid] = Bmat[tid]; }
    if (tid < 2)  counters[tid] = 0;
    for (int t = tid; t < 4096; t += 256) hist[t] = 0;

    const float qp0 = qpos[q * 2 + 0];
    const float qp1 = qpos[q * 2 + 1];
    __syncthreads();

    float lmin = 1e30f;
    for (int v = tid; v < 2048; v += 256) {
        float d0 = qp0 - pos[v * 2 + 0];
        float d1 = qp1 - pos[v * 2 + 1];
        d0 += 0.5f; d0 -= floorf(d0); d0 -= 0.5f;
        d1 += 0.5f; d1 -= floorf(d1); d1 -= 0.5f;
        float e = d0 * d0 + d1 * d1;
        ebits[v] = __float_as_uint(e);
        lmin = fminf(lmin, e);
        int bb = (int)(e * 8192.0f); bb = (bb > 4095) ? 4095 : bb;
        atomicAdd(&hist[bb], 1u);
    }
    sred[tid] = lmin;
    __syncthreads();
    for (int s = 128; s > 0; s >>= 1) {
        if (tid < s) sred[tid] = fminf(sred[tid], sred[tid + s]);
        __syncthreads();
    }
    const float e_min = sred[0];
    __syncthreads();

    unsigned lsum = 0;
    #pragma unroll
    for (int i = 0; i < 16; ++i) lsum += hist[tid * 16 + i];
    unsigned vq = lsum;
    #pragma unroll
    for (int off = 1; off < 64; off <<= 1) {
        unsigned n = __shfl_up(vq, off, 64);
        if (lane >= off) vq += n;
    }
    if (lane == 63) wsum[wid] = vq;
    __syncthreads();
    unsigned base = 0;
    for (int w2 = 0; w2 < wid; ++w2) base += wsum[w2];
    unsigned cum = base + vq - lsum;
    #pragma unroll
    for (int i = 0; i < 16; ++i) {
        unsigned cnt = hist[tid * 16 + i];
        if (cum <= 102u && 102u < cum + cnt) { info[0] = tid * 16 + i; info[1] = (int)cum; }
        cum += cnt;
    }
    __syncthreads();
    const int Bstar = info[0];
    const int L = info[1];
    const int need = K_SEL - L;

    for (int v = tid; v < 2048; v += 256) {
        unsigned bb = ebits[v];
        float e = __uint_as_float(bb);
        int bin = (int)(e * 8192.0f); bin = (bin > 4095) ? 4095 : bin;
        if (bin < Bstar) {
            int s2 = atomicAdd(&counters[0], 1);
            sel_v[s2] = v; sel_e[s2] = e;
        } else if (bin == Bstar) {
            int s2 = atomicAdd(&counters[1], 1);
            if (s2 < 128) bnd[s2] = (((ull_t)bb) << 32) | (unsigned)v;
        }
    }
    __syncthreads();
    if (tid == 0) {
        int nb = counters[1]; if (nb > 128) nb = 128;
        for (int i = 1; i < nb; ++i) {
            ull_t key = bnd[i]; int j2 = i - 1;
            while (j2 >= 0 && bnd[j2] > key) { bnd[j2 + 1] = bnd[j2]; --j2; }
            bnd[j2 + 1] = key;
        }
        for (int i = 0; i < need; ++i) {
            sel_v[L + i] = (int)(unsigned)(bnd[i] & 0xffffffffull);
            sel_e[L + i] = __uint_as_float((unsigned)(bnd[i] >> 32));
        }
        emax_s = __uint_as_float((unsigned)(bnd[need - 1] >> 32));
    }
    __syncthreads();

    const float denom = (emax_s - e_min) + 1e-8f;
    float w = 0.0f;
    if (tid < K_SEL) w = __expf(-(sel_e[tid] - e_min) / denom);
    if (tid < K_SEL) sel_e[tid] = w;
    if (tid < 128) sred[tid] = (tid < K_SEL) ? w : 0.0f;
    __syncthreads();
    for (int s = 64; s > 0; s >>= 1) {
        if (tid < s) sred[tid] += sred[tid + s];
        __syncthreads();
    }
    const float total = sred[0];

    if (tid < 2 * K_SEL) {
        const int k = tid >> 1;
        const int io = (tid & 1) * 16;
        const int v = sel_v[k];
        const float kd = sel_e[k] / total;
        float d0 = qp0 - pos[v * 2 + 0];
        float d1 = qp1 - pos[v * 2 + 1];
        d0 += 0.5f; d0 -= floorf(d0); d0 -= 0.5f;
        d1 += 0.5f; d1 -= floorf(d1); d1 -= 0.5f;
        float kf[32];
        #pragma unroll
        for (int f = 0; f < 16; ++f) {
            float t = d0 * Bm[f] + d1 * Bm[16 + f];   // revolutions
            float r = t - rintf(t);
            kf[f]      = __builtin_amdgcn_sinf(r);
            kf[16 + f] = __builtin_amdgcn_cosf(r);
        }
        float* hout = Hg + ((size_t)q * K_SEL + k) * 36;
        #pragma unroll 4
        for (int i = io; i < io + 16; ++i) {
            float pre = b1s[i];
            #pragma unroll
            for (int jf = 0; jf < 32; ++jf) pre += kf[jf] * W1s[i * 32 + jf];
            float g = 0.5f * pre * (1.0f + erff(pre * 0.70710678118654752f));
            hout[i] = g * kd;
        }
        if ((tid & 1) == 0) {
            hout[32] = kd;
            indg[q * K_SEL + k] = v;
        }
    }
}

// ---------------- K3: fused per (q, bt-half): GEMM1 + GEMM2 -----------------
// Wave w <-> bt w. Xg staged fp16 in LDS for all 4 bt (one sync).
// GEMM1: thread=(bt=wave, jg, cg), tile 4j x 8c: per k 1 ds_read_b128 (x) +
//        1 global dwordx4 (H, L1-hot) -> 32 FMA. Zs bf16 c-major (8-way wr).
// GEMM2: one W2t pass, uint2 Zs reads (2-way, free), LDS reduce.
__global__ __launch_bounds__(256) void k3_main(const _Float16* __restrict__ xlh,
                                               const float* __restrict__ Hg,
                                               const int* __restrict__ indg,
                                               const float* __restrict__ W2t,
                                               const float* __restrict__ bias,
                                               float* __restrict__ out) {
    const int bid = blockIdx.x;
    const int q = bid >> 1;
    const int bt0 = (bid & 1) * 4;
    const int tid = threadIdx.x;

    __shared__ _Float16 Xgs[4][K_SEL][64];   // 52.7 KB
    __shared__ ushort_t Zs[2112 * 4];        // 16.9 KB, [zidx][bt] bf16
    __shared__ int ind_s[K_SEL];
    float* red = (float*)&Xgs[0][0][0];      // 16 KB alias, used after GEMM2

    if (tid < K_SEL) ind_s[tid] = indg[q * K_SEL + tid];
    __syncthreads();

    // ---- gather: Xgs[bt][k][c] = xlh[bt0+bt][ind[k]][c]  (half8 coalesced)
    for (int t = tid; t < 4 * K_SEL * 8; t += 256) {
        int bt = t / (K_SEL * 8);
        int r = t - bt * (K_SEL * 8);
        int row = r >> 3;
        int part = r & 7;
        const _Float16* src = xlh + ((size_t)(bt0 + bt) * 2048 + ind_s[row]) * 64 + part * 8;
        *(half8*)&Xgs[bt][row][part * 8] = *(const half8*)src;
    }
    __syncthreads();

    // ---- GEMM1: acc[jj][cc] over k
    const int bt = tid >> 6;           // wave index
    const int jg = (tid >> 3) & 7;     // j0 = jg*4
    const int cg = tid & 7;            // c0 = cg*8
    const float* hgq = Hg + (size_t)q * (K_SEL * 36);
    const float4* hp = (const float4*)hgq;   // index k*9 + jg

    float acc[4][8];
    #pragma unroll
    for (int jj = 0; jj < 4; ++jj)
        #pragma unroll
        for (int cc = 0; cc < 8; ++cc) acc[jj][cc] = 0.0f;

    const _Float16* xbase = &Xgs[bt][0][cg * 8];
    for (int k = 0; k < K_SEL; ++k) {
        half8 xv = *(const half8*)(xbase + k * 64);
        float4 hv = hp[k * 9 + jg];
        float h0 = hv.x, h1 = hv.y, h2 = hv.z, h3 = hv.w;
        #pragma unroll
        for (int cc = 0; cc < 8; ++cc) {
            float xf = (float)xv[cc];
            acc[0][cc] += h0 * xf;
            acc[1][cc] += h1 * xf;
            acc[2][cc] += h2 * xf;
            acc[3][cc] += h3 * xf;
        }
    }
    #pragma unroll
    for (int jj = 0; jj < 4; ++jj)
        #pragma unroll
        for (int cc = 0; cc < 8; ++cc) {
            int zidx = (cg * 8 + cc) * 33 + (jg * 4 + jj);
            Zs[zidx * 4 + bt] = f2bf(acc[jj][cc]);
        }

    // ---- filt row (j=32): z[c] = sum_k kd_k * x[k][c], threads 0..31
    if (tid < 32) {
        const int btf = tid >> 3;
        const int cgf = tid & 7;
        const float* hk = hgq + 32;     // Hg[q][k][32], stride 36
        float fa[8];
        #pragma unroll
        for (int cc = 0; cc < 8; ++cc) fa[cc] = 0.0f;
        const _Float16* xb = &Xgs[btf][0][cgf * 8];
        for (int k = 0; k < K_SEL; ++k) {
            half8 xv = *(const half8*)(xb + k * 64);
            float kd = hk[k * 36];
            #pragma unroll
            for (int cc = 0; cc < 8; ++cc) fa[cc] += kd * (float)xv[cc];
        }
        #pragma unroll
        for (int cc = 0; cc < 8; ++cc)
            Zs[((cgf * 8 + cc) * 33 + 32) * 4 + btf] = f2bf(fa[cc]);
    }
    __syncthreads();

    // ---- GEMM2: one W2t pass; thread = (eg = tid>>3, d0 = (tid&7)*4)
    const int eg = tid >> 3;
    const int d0v = (tid & 7) * 4;
    float oa[4][4];
    #pragma unroll
    for (int b2 = 0; b2 < 4; ++b2)
        #pragma unroll
        for (int i = 0; i < 4; ++i) oa[b2][i] = 0.0f;

    for (int ii = 0; ii < 66; ++ii) {
        int e = ii * 32 + eg;
        int j = e >> 6, c = e & 63;
        int zidx = c * 33 + j;
        float4 w = *(const float4*)(W2t + (size_t)e * 32 + d0v);
        uint2 zp = *(const uint2*)(&Zs[zidx * 4]);
        float z0 = __uint_as_float(zp.x << 16);
        float z1 = __uint_as_float(zp.x & 0xffff0000u);
        float z2 = __uint_as_float(zp.y << 16);
        float z3 = __uint_as_float(zp.y & 0xffff0000u);
        oa[0][0] += z0 * w.x; oa[0][1] += z0 * w.y; oa[0][2] += z0 * w.z; oa[0][3] += z0 * w.w;
        oa[1][0] += z1 * w.x; oa[1][1] += z1 * w.y; oa[1][2] += z1 * w.z; oa[1][3] += z1 * w.w;
        oa[2][0] += z2 * w.x; oa[2][1] += z2 * w.y; oa[2][2] += z2 * w.z; oa[2][3] += z2 * w.w;
        oa[3][0] += z3 * w.x; oa[3][1] += z3 * w.y; oa[3][2] += z3 * w.z; oa[3][3] += z3 * w.w;
    }
    __syncthreads();   // Xgs fully dead; red aliases it
    #pragma unroll
    for (int b2 = 0; b2 < 4; ++b2)
        #pragma unroll
        for (int i = 0; i < 4; ++i)
            red[eg * 128 + b2 * 32 + d0v + i] = oa[b2][i];
    __syncthreads();
    if (tid < 128) {
        const int btw = tid >> 5;
        const int d = tid & 31;
        float s = bias[d];
        #pragma unroll
        for (int p = 0; p < 32; ++p) s += red[p * 128 + tid];
        out[((size_t)(bt0 + btw) * 512 + q) * 32 + d] = s;
    }
}

// ---------------------------------------------------------------------------
extern "C" void kernel_launch(void* const* d_in, const int* in_sizes, int n_in,
                              void* d_out, int out_size, void* d_ws, size_t ws_size,
                              hipStream_t stream) {
    const float* x     = (const float*)d_in[0];   // (2,4,2048,64)
    const float* pos   = (const float*)d_in[1];   // (2048,2)
    const float* qpos  = (const float*)d_in[2];   // (512,2)
    const float* W_lin = (const float*)d_in[3];   // (64,64)
    const float* b_lin = (const float*)d_in[4];   // (64)
    const float* Bmat  = (const float*)d_in[5];   // (2,16)
    const float* W1    = (const float*)d_in[6];   // (32,32)
    const float* b1    = (const float*)d_in[7];   // (32)
    const float* W2    = (const float*)d_in[8];   // (2048,32)
    const float* filt  = (const float*)d_in[9];   // (2048)
    const float* bias  = (const float*)d_in[10];  // (32)
    float* out = (float*)d_out;

    float* ws = (float*)d_ws;
    _Float16* xlh = (_Float16*)ws;         // 16384*64 halfs = 524288 floats
    float* Hg   = ws + 524288;             // 512*103*36  = 1898496 floats
    int*   indg = (int*)(ws + 2422784);    // 512*103     = 52736 ints
    float* W2t  = ws + 2475520;            // 2112*32     = 67584 floats

    k1_lin<<<1024, 256, 0, stream>>>(x, W_lin, b_lin, xlh, W2, filt, W2t);
    k2_select<<<512, 256, 0, stream>>>(pos, qpos, Bmat, W1, b1, Hg, indg);
    k3_main<<<1024, 256, 0, stream>>>(xlh, Hg, indg, W2t, bias, out);
}

// Round 5
// 175.009 us; speedup vs baseline: 1.2800x; 1.0787x over previous
//
#include <hip/hip_runtime.h>

#define K_SEL 103
typedef unsigned long long ull_t;
typedef _Float16 f16x8 __attribute__((ext_vector_type(8)));
typedef float f32x4 __attribute__((ext_vector_type(4)));

// ---------------- K1: xlh = fp16(x @ W_lin^T + b_lin), + W2th build ---------
// W2th[d][e] fp16, e = j*64+c (j<33): row-32 = filt. 32 x 2112.
__global__ __launch_bounds__(256) void k1_lin(const float* __restrict__ x,
                                              const float* __restrict__ W,
                                              const float* __restrict__ b,
                                              _Float16* __restrict__ xlh,
                                              const float* __restrict__ W2,
                                              const float* __restrict__ filt,
                                              _Float16* __restrict__ W2th) {
    // fold: 1024 blocks x 66 = 67584 = 2112*32 exactly
    if (threadIdx.x < 66) {
        int t = blockIdx.x * 66 + threadIdx.x;
        int d = t & 31;
        int e = t >> 5;
        int c = e & 63;
        int j = e >> 6;
        float v = (j < 32) ? W2[(c * 32 + d) * 32 + j] : filt[c * 32 + d];
        W2th[d * 2112 + e] = (_Float16)v;
    }
    __shared__ float Wt[64 * 64];   // Wt[j*64+i] = W[i*64+j]
    for (int t = threadIdx.x; t < 4096; t += 256)
        Wt[(t & 63) * 64 + (t >> 6)] = W[t];
    __syncthreads();
    int i = threadIdx.x & 63;
    int sub = threadIdx.x >> 6;
    int r0 = blockIdx.x * 16 + sub * 4;
    float bi = b[i];
    float acc0 = bi, acc1 = bi, acc2 = bi, acc3 = bi;
    const float* xr = x + (size_t)r0 * 64;
    #pragma unroll 4
    for (int jj = 0; jj < 16; ++jj) {
        float4 v0 = *(const float4*)(xr + 0 * 64 + jj * 4);
        float4 v1 = *(const float4*)(xr + 1 * 64 + jj * 4);
        float4 v2 = *(const float4*)(xr + 2 * 64 + jj * 4);
        float4 v3 = *(const float4*)(xr + 3 * 64 + jj * 4);
        float w0 = Wt[(jj * 4 + 0) * 64 + i];
        float w1 = Wt[(jj * 4 + 1) * 64 + i];
        float w2 = Wt[(jj * 4 + 2) * 64 + i];
        float w3 = Wt[(jj * 4 + 3) * 64 + i];
        acc0 += v0.x * w0 + v0.y * w1 + v0.z * w2 + v0.w * w3;
        acc1 += v1.x * w0 + v1.y * w1 + v1.z * w2 + v1.w * w3;
        acc2 += v2.x * w0 + v2.y * w1 + v2.z * w2 + v2.w * w3;
        acc3 += v3.x * w0 + v3.y * w1 + v3.z * w2 + v3.w * w3;
    }
    xlh[(size_t)(r0 + 0) * 64 + i] = (_Float16)acc0;
    xlh[(size_t)(r0 + 1) * 64 + i] = (_Float16)acc1;
    xlh[(size_t)(r0 + 2) * 64 + i] = (_Float16)acc2;
    xlh[(size_t)(r0 + 3) * 64 + i] = (_Float16)acc3;
}

// ---------------- K2a: per-query neighbor select (histogram) ----------------
// Outputs indg[q][k], kdg[q][k] (softmax weight). Slot order arbitrary.
__global__ __launch_bounds__(256) void k2a_select(const float* __restrict__ pos,
                                                  const float* __restrict__ qpos,
                                                  int* __restrict__ indg,
                                                  float* __restrict__ kdg) {
    const int q = blockIdx.x;
    const int tid = threadIdx.x;
    const int lane = tid & 63;
    const int wid = tid >> 6;

    __shared__ unsigned ebits[2048];
    __shared__ unsigned hist[4096];
    __shared__ float sred[256];
    __shared__ int   sel_v[K_SEL];
    __shared__ float sel_e[K_SEL];
    __shared__ ull_t bnd[128];
    __shared__ int   counters[2];
    __shared__ int   info[2];
    __shared__ unsigned wsum[4];
    __shared__ float emax_s;

    if (tid < 2) counters[tid] = 0;
    for (int t = tid; t < 4096; t += 256) hist[t] = 0;

    const float qp0 = qpos[q * 2 + 0];
    const float qp1 = qpos[q * 2 + 1];
    __syncthreads();

    float lmin = 1e30f;
    for (int v = tid; v < 2048; v += 256) {
        float d0 = qp0 - pos[v * 2 + 0];
        float d1 = qp1 - pos[v * 2 + 1];
        d0 += 0.5f; d0 -= floorf(d0); d0 -= 0.5f;
        d1 += 0.5f; d1 -= floorf(d1); d1 -= 0.5f;
        float e = d0 * d0 + d1 * d1;
        ebits[v] = __float_as_uint(e);
        lmin = fminf(lmin, e);
        int bb = (int)(e * 8192.0f); bb = (bb > 4095) ? 4095 : bb;
        atomicAdd(&hist[bb], 1u);
    }
    sred[tid] = lmin;
    __syncthreads();
    for (int s = 128; s > 0; s >>= 1) {
        if (tid < s) sred[tid] = fminf(sred[tid], sred[tid + s]);
        __syncthreads();
    }
    const float e_min = sred[0];
    __syncthreads();

    unsigned lsum = 0;
    #pragma unroll
    for (int i = 0; i < 16; ++i) lsum += hist[tid * 16 + i];
    unsigned vq = lsum;
    #pragma unroll
    for (int off = 1; off < 64; off <<= 1) {
        unsigned n = __shfl_up(vq, off, 64);
        if (lane >= off) vq += n;
    }
    if (lane == 63) wsum[wid] = vq;
    __syncthreads();
    unsigned base = 0;
    for (int w2 = 0; w2 < wid; ++w2) base += wsum[w2];
    unsigned cum = base + vq - lsum;
    #pragma unroll
    for (int i = 0; i < 16; ++i) {
        unsigned cnt = hist[tid * 16 + i];
        if (cum <= 102u && 102u < cum + cnt) { info[0] = tid * 16 + i; info[1] = (int)cum; }
        cum += cnt;
    }
    __syncthreads();
    const int Bstar = info[0];
    const int L = info[1];
    const int need = K_SEL - L;

    for (int v = tid; v < 2048; v += 256) {
        unsigned bb = ebits[v];
        float e = __uint_as_float(bb);
        int bin = (int)(e * 8192.0f); bin = (bin > 4095) ? 4095 : bin;
        if (bin < Bstar) {
            int s2 = atomicAdd(&counters[0], 1);
            sel_v[s2] = v; sel_e[s2] = e;
        } else if (bin == Bstar) {
            int s2 = atomicAdd(&counters[1], 1);
            if (s2 < 128) bnd[s2] = (((ull_t)bb) << 32) | (unsigned)v;
        }
    }
    __syncthreads();
    if (tid == 0) {
        int nb = counters[1]; if (nb > 128) nb = 128;
        for (int i = 1; i < nb; ++i) {
            ull_t key = bnd[i]; int j2 = i - 1;
            while (j2 >= 0 && bnd[j2] > key) { bnd[j2 + 1] = bnd[j2]; --j2; }
            bnd[j2 + 1] = key;
        }
        for (int i = 0; i < need; ++i) {
            sel_v[L + i] = (int)(unsigned)(bnd[i] & 0xffffffffull);
            sel_e[L + i] = __uint_as_float((unsigned)(bnd[i] >> 32));
        }
        emax_s = __uint_as_float((unsigned)(bnd[need - 1] >> 32));
    }
    __syncthreads();

    const float denom = (emax_s - e_min) + 1e-8f;
    float w = 0.0f;
    if (tid < K_SEL) w = __expf(-(sel_e[tid] - e_min) / denom);
    if (tid < 128) sred[tid] = (tid < K_SEL) ? w : 0.0f;
    __syncthreads();
    for (int s = 64; s > 0; s >>= 1) {
        if (tid < s) sred[tid] += sred[tid + s];
        __syncthreads();
    }
    const float total = sred[0];

    if (tid < K_SEL) {
        indg[q * K_SEL + tid] = sel_v[tid];
        kdg[q * K_SEL + tid] = w / total;
    }
}

// ---------------- K2b: kernel-MLP -> Hh[q][48][128] fp16 (A-operand layout) -
// Hh[q][j][k] = gelu(mlp)_j * kd (j<32); row 32 = kd; rows 33..47 & k>=103 = 0.
__global__ __launch_bounds__(128) void k2b_mlp(const float* __restrict__ pos,
                                               const float* __restrict__ qpos,
                                               const float* __restrict__ Bmat,
                                               const float* __restrict__ W1,
                                               const float* __restrict__ b1,
                                               const int* __restrict__ indg,
                                               const float* __restrict__ kdg,
                                               _Float16* __restrict__ Hh) {
    const int q = blockIdx.x;
    const int tid = threadIdx.x;
    __shared__ float W1s[1024];
    __shared__ float b1s[32];
    __shared__ float Bm[32];
    for (int t = tid; t < 1024; t += 128) W1s[t] = W1[t];
    if (tid < 32) { b1s[tid] = b1[tid]; Bm[tid] = Bmat[tid]; }

    _Float16* hq = Hh + (size_t)q * 48 * 128;
    // zero the complement regions (disjoint from fills -> no barrier needed):
    // A: all j, k in [103,128); B: j in [33,48), k in [0,103)
    for (int t = tid; t < 1200; t += 128) {        // 48*25
        int j = t / 25, k = 103 + t % 25;
        hq[j * 128 + k] = (_Float16)0.0f;
    }
    for (int t = tid; t < 1545; t += 128) {        // 15*103
        int j = 33 + t / 103, k = t % 103;
        hq[j * 128 + k] = (_Float16)0.0f;
    }
    __syncthreads();

    if (tid < K_SEL) {
        const int k = tid;
        const int v = indg[q * K_SEL + k];
        const float kd = kdg[q * K_SEL + k];
        const float qp0 = qpos[q * 2 + 0];
        const float qp1 = qpos[q * 2 + 1];
        float d0 = qp0 - pos[v * 2 + 0];
        float d1 = qp1 - pos[v * 2 + 1];
        d0 += 0.5f; d0 -= floorf(d0); d0 -= 0.5f;
        d1 += 0.5f; d1 -= floorf(d1); d1 -= 0.5f;
        float kf[32];
        #pragma unroll
        for (int f = 0; f < 16; ++f) {
            float t = d0 * Bm[f] + d1 * Bm[16 + f];   // revolutions
            float r = t - rintf(t);
            kf[f]      = __builtin_amdgcn_sinf(r);
            kf[16 + f] = __builtin_amdgcn_cosf(r);
        }
        _Float16* hc = hq + k;          // column k, row-stride 128
        #pragma unroll 4
        for (int i = 0; i < 32; ++i) {
            float pre = b1s[i];
            #pragma unroll
            for (int jf = 0; jf < 32; ++jf) pre += kf[jf] * W1s[i * 32 + jf];
            float g = 0.5f * pre * (1.0f + erff(pre * 0.70710678118654752f));
            hc[i * 128] = (_Float16)(g * kd);
        }
        hc[32 * 128] = (_Float16)kd;
    }
}

// ---------------- K3: MFMA GEMM1 + GEMM2, block = (q, bt-pair) --------------
// GEMM1: Z[j, (bt,c)] = sum_k Hh[q][j][k] * Xg[bt][k][c]; M=48(33), N=128, K=128
// GEMM2: out[bt, d]   = sum_e Zh[bt][e] * W2th[d][e];     M=16(2), N=32, K=2112
__global__ __launch_bounds__(256, 3) void k3_main(const _Float16* __restrict__ xlh,
                                                  const _Float16* __restrict__ Hh,
                                                  const int* __restrict__ indg,
                                                  const _Float16* __restrict__ W2th,
                                                  const float* __restrict__ bias,
                                                  float* __restrict__ out) {
    const int bid = blockIdx.x;
    const int q = bid >> 2;
    const int bt0 = (bid & 3) * 2;
    const int tid = threadIdx.x;
    const int lane = tid & 63;
    const int wv = tid >> 6;
    const int n0 = lane & 15;
    const int quad = lane >> 4;

    __shared__ __align__(16) _Float16 XgT[2][64][136];   // 34.8 KB (pad 136)
    __shared__ __align__(16) _Float16 Zh[2][2112];       // 8.4 KB, e-contiguous
    __shared__ float red[4][2][2][16];                   // wave, dtile, bt, d16
    __shared__ int ind_s[K_SEL];

    if (tid < K_SEL) ind_s[tid] = indg[q * K_SEL + tid];
    __syncthreads();

    // ---- gather + transpose: XgT[bt][c][k] = xlh[bt0+bt][ind[k]][c]
    for (int t = tid; t < 1648; t += 256) {              // 2*103*8
        int bt = t / 824;
        int r = t - bt * 824;
        int k = r >> 3;
        int oct = r & 7;
        const _Float16* src = xlh + ((size_t)(bt0 + bt) * 2048 + ind_s[k]) * 64 + oct * 8;
        f16x8 v = *(const f16x8*)src;
        #pragma unroll
        for (int i = 0; i < 8; ++i) XgT[bt][oct * 8 + i][k] = v[i];
    }
    // zero-pad k in [103,128)
    for (int t = tid; t < 3200; t += 256) {              // 2*64*25
        int bt = t / 1600;
        int r = t - bt * 1600;
        int c = r / 25;
        int k = 103 + (r - c * 25);
        XgT[bt][c][k] = (_Float16)0.0f;
    }
    __syncthreads();

    // ---- GEMM1: wave wv covers n-tiles ct = {2wv, 2wv+1}, all 3 row-tiles
    f32x4 Dz[3][2];
    #pragma unroll
    for (int r = 0; r < 3; ++r)
        #pragma unroll
        for (int c = 0; c < 2; ++c) Dz[r][c] = (f32x4){0.f, 0.f, 0.f, 0.f};

    const _Float16* hq = Hh + (size_t)q * 48 * 128;
    #pragma unroll
    for (int ks = 0; ks < 4; ++ks) {
        const int kbase = ks * 32 + quad * 8;
        f16x8 afr[3];
        #pragma unroll
        for (int r = 0; r < 3; ++r)
            afr[r] = *(const f16x8*)(hq + (r * 16 + n0) * 128 + kbase);
        #pragma unroll
        for (int ctl = 0; ctl < 2; ++ctl) {
            const int ct = wv * 2 + ctl;
            const int bt = ct >> 2;
            const int c = (ct & 3) * 16 + n0;
            f16x8 bfr = *(const f16x8*)(&XgT[bt][c][kbase]);
            #pragma unroll
            for (int r = 0; r < 3; ++r)
                Dz[r][ctl] = __builtin_amdgcn_mfma_f32_16x16x32_f16(afr[r], bfr, Dz[r][ctl], 0, 0, 0);
        }
    }
    // write Z tiles -> Zh[bt][e], e = j*64 + c  (C-layout: row=quad*4+reg, col=n0)
    #pragma unroll
    for (int ctl = 0; ctl < 2; ++ctl) {
        const int ct = wv * 2 + ctl;
        const int bt = ct >> 2;
        const int c = (ct & 3) * 16 + n0;
        #pragma unroll
        for (int r = 0; r < 3; ++r)
            #pragma unroll
            for (int reg = 0; reg < 4; ++reg) {
                int j = r * 16 + quad * 4 + reg;
                if (j < 33) Zh[bt][j * 64 + c] = (_Float16)Dz[r][ctl][reg];
            }
    }
    __syncthreads();

    // ---- GEMM2: steps s = wv, wv+4, ... (66 steps of K=32)
    f32x4 D2[2];
    D2[0] = (f32x4){0.f, 0.f, 0.f, 0.f};
    D2[1] = (f32x4){0.f, 0.f, 0.f, 0.f};
    for (int s = wv; s < 66; s += 4) {
        const int e0 = s * 32 + quad * 8;
        f16x8 afr = {0, 0, 0, 0, 0, 0, 0, 0};
        if (n0 < 2) afr = *(const f16x8*)(&Zh[n0][e0]);
        #pragma unroll
        for (int dt = 0; dt < 2; ++dt) {
            f16x8 bfr = *(const f16x8*)(W2th + (size_t)(dt * 16 + n0) * 2112 + e0);
            D2[dt] = __builtin_amdgcn_mfma_f32_16x16x32_f16(afr, bfr, D2[dt], 0, 0, 0);
        }
    }
    // rows m = quad*4+reg: bt rows 0,1 live in quad 0, regs 0,1
    if (quad == 0) {
        red[wv][0][0][n0] = D2[0][0];
        red[wv][0][1][n0] = D2[0][1];
        red[wv][1][0][n0] = D2[1][0];
        red[wv][1][1][n0] = D2[1][1];
    }
    __syncthreads();
    if (tid < 64) {
        const int bt = tid >> 5;
        const int d = tid & 31;
        const int dt = d >> 4;
        const int dn = d & 15;
        float s = bias[d];
        #pragma unroll
        for (int w2 = 0; w2 < 4; ++w2) s += red[w2][dt][bt][dn];
        out[((size_t)(bt0 + bt) * 512 + q) * 32 + d] = s;
    }
}

// ---------------------------------------------------------------------------
extern "C" void kernel_launch(void* const* d_in, const int* in_sizes, int n_in,
                              void* d_out, int out_size, void* d_ws, size_t ws_size,
                              hipStream_t stream) {
    const float* x     = (const float*)d_in[0];   // (2,4,2048,64)
    const float* pos   = (const float*)d_in[1];   // (2048,2)
    const float* qpos  = (const float*)d_in[2];   // (512,2)
    const float* W_lin = (const float*)d_in[3];   // (64,64)
    const float* b_lin = (const float*)d_in[4];   // (64)
    const float* Bmat  = (const float*)d_in[5];   // (2,16)
    const float* W1    = (const float*)d_in[6];   // (32,32)
    const float* b1    = (const float*)d_in[7];   // (32)
    const float* W2    = (const float*)d_in[8];   // (2048,32)
    const float* filt  = (const float*)d_in[9];   // (2048)
    const float* bias  = (const float*)d_in[10];  // (32)
    float* out = (float*)d_out;

    float* ws = (float*)d_ws;
    _Float16* xlh  = (_Float16*)ws;                 // 1048576 halfs = 524288 f
    _Float16* Hh   = (_Float16*)(ws + 524288);      // 512*48*128 halfs = 1572864 f
    int*      indg = (int*)(ws + 2097152);          // 52736
    float*    kdg  = ws + 2149888;                  // 52736
    _Float16* W2th = (_Float16*)(ws + 2202624);     // 32*2112 halfs = 33792 f

    k1_lin<<<1024, 256, 0, stream>>>(x, W_lin, b_lin, xlh, W2, filt, W2th);
    k2a_select<<<512, 256, 0, stream>>>(pos, qpos, indg, kdg);
    k2b_mlp<<<512, 128, 0, stream>>>(pos, qpos, Bmat, W1, b1, indg, kdg, Hh);
    k3_main<<<2048, 256, 0, stream>>>(xlh, Hh, indg, W2th, bias, out);
}

// Round 6
// 162.534 us; speedup vs baseline: 1.3782x; 1.0768x over previous
//
#include <hip/hip_runtime.h>

#define K_SEL 103
typedef unsigned long long ull_t;
typedef _Float16 f16x8 __attribute__((ext_vector_type(8)));
typedef float f32x4 __attribute__((ext_vector_type(4)));

// ---------------- K1: xlh = fp16(x @ W_lin^T + b_lin), + W2th build ---------
// W2th[d][e] fp16, e = j*64+c (j<33): row-32 = filt. 32 x 2112.
__global__ __launch_bounds__(256) void k1_lin(const float* __restrict__ x,
                                              const float* __restrict__ W,
                                              const float* __restrict__ b,
                                              _Float16* __restrict__ xlh,
                                              const float* __restrict__ W2,
                                              const float* __restrict__ filt,
                                              _Float16* __restrict__ W2th) {
    if (threadIdx.x < 66) {
        int t = blockIdx.x * 66 + threadIdx.x;
        int d = t & 31;
        int e = t >> 5;
        int c = e & 63;
        int j = e >> 6;
        float v = (j < 32) ? W2[(c * 32 + d) * 32 + j] : filt[c * 32 + d];
        W2th[d * 2112 + e] = (_Float16)v;
    }
    __shared__ float Wt[64 * 64];   // Wt[j*64+i] = W[i*64+j]
    for (int t = threadIdx.x; t < 4096; t += 256)
        Wt[(t & 63) * 64 + (t >> 6)] = W[t];
    __syncthreads();
    int i = threadIdx.x & 63;
    int sub = threadIdx.x >> 6;
    int r0 = blockIdx.x * 16 + sub * 4;
    float bi = b[i];
    float acc0 = bi, acc1 = bi, acc2 = bi, acc3 = bi;
    const float* xr = x + (size_t)r0 * 64;
    #pragma unroll 4
    for (int jj = 0; jj < 16; ++jj) {
        float4 v0 = *(const float4*)(xr + 0 * 64 + jj * 4);
        float4 v1 = *(const float4*)(xr + 1 * 64 + jj * 4);
        float4 v2 = *(const float4*)(xr + 2 * 64 + jj * 4);
        float4 v3 = *(const float4*)(xr + 3 * 64 + jj * 4);
        float w0 = Wt[(jj * 4 + 0) * 64 + i];
        float w1 = Wt[(jj * 4 + 1) * 64 + i];
        float w2 = Wt[(jj * 4 + 2) * 64 + i];
        float w3 = Wt[(jj * 4 + 3) * 64 + i];
        acc0 += v0.x * w0 + v0.y * w1 + v0.z * w2 + v0.w * w3;
        acc1 += v1.x * w0 + v1.y * w1 + v1.z * w2 + v1.w * w3;
        acc2 += v2.x * w0 + v2.y * w1 + v2.z * w2 + v2.w * w3;
        acc3 += v3.x * w0 + v3.y * w1 + v3.z * w2 + v3.w * w3;
    }
    xlh[(size_t)(r0 + 0) * 64 + i] = (_Float16)acc0;
    xlh[(size_t)(r0 + 1) * 64 + i] = (_Float16)acc1;
    xlh[(size_t)(r0 + 2) * 64 + i] = (_Float16)acc2;
    xlh[(size_t)(r0 + 3) * 64 + i] = (_Float16)acc3;
}

// ---------------- K2: select (histogram) + MLP -> Hh (merged) ---------------
// Hh[q][48][128] fp16 A-operand layout; rows>=33 & k>=103 zero.
__global__ __launch_bounds__(256) void k2_select(const float* __restrict__ pos,
                                                 const float* __restrict__ qpos,
                                                 const float* __restrict__ Bmat,
                                                 const float* __restrict__ W1,
                                                 const float* __restrict__ b1,
                                                 _Float16* __restrict__ Hh,
                                                 int* __restrict__ indg) {
    const int q = blockIdx.x;
    const int tid = threadIdx.x;
    const int lane = tid & 63;
    const int wid = tid >> 6;

    __shared__ unsigned ebits[2048];
    __shared__ unsigned hist[4096];
    __shared__ float W1s[1024];
    __shared__ _Float16 Hs[48 * 128];
    __shared__ float b1s[32];
    __shared__ float Bm[32];
    __shared__ float sred[256];
    __shared__ int   sel_v[K_SEL];
    __shared__ float sel_e[K_SEL];
    __shared__ ull_t bnd[128];
    __shared__ int   counters[2];
    __shared__ int   info[2];
    __shared__ unsigned wsum[4];
    __shared__ float emax_s;

    for (int t = tid; t < 1024; t += 256) W1s[t] = W1[t];
    if (tid < 32) { b1s[tid] = b1[tid]; Bm[tid] = Bmat[tid]; }
    if (tid < 2)  counters[tid] = 0;
    for (int t = tid; t < 4096; t += 256) hist[t] = 0;
    {   // zero H staging (half8 wide)
        f16x8 z = {0, 0, 0, 0, 0, 0, 0, 0};
        for (int t = tid; t < 768; t += 256) *(f16x8*)(&Hs[t * 8]) = z;
    }

    const float qp0 = qpos[q * 2 + 0];
    const float qp1 = qpos[q * 2 + 1];
    __syncthreads();

    float lmin = 1e30f;
    for (int v = tid; v < 2048; v += 256) {
        float d0 = qp0 - pos[v * 2 + 0];
        float d1 = qp1 - pos[v * 2 + 1];
        d0 += 0.5f; d0 -= floorf(d0); d0 -= 0.5f;
        d1 += 0.5f; d1 -= floorf(d1); d1 -= 0.5f;
        float e = d0 * d0 + d1 * d1;
        ebits[v] = __float_as_uint(e);
        lmin = fminf(lmin, e);
        int bb = (int)(e * 8192.0f); bb = (bb > 4095) ? 4095 : bb;
        atomicAdd(&hist[bb], 1u);
    }
    sred[tid] = lmin;
    __syncthreads();
    for (int s = 128; s > 0; s >>= 1) {
        if (tid < s) sred[tid] = fminf(sred[tid], sred[tid + s]);
        __syncthreads();
    }
    const float e_min = sred[0];
    __syncthreads();

    unsigned lsum = 0;
    #pragma unroll
    for (int i = 0; i < 16; ++i) lsum += hist[tid * 16 + i];
    unsigned vq = lsum;
    #pragma unroll
    for (int off = 1; off < 64; off <<= 1) {
        unsigned n = __shfl_up(vq, off, 64);
        if (lane >= off) vq += n;
    }
    if (lane == 63) wsum[wid] = vq;
    __syncthreads();
    unsigned base = 0;
    for (int w2 = 0; w2 < wid; ++w2) base += wsum[w2];
    unsigned cum = base + vq - lsum;
    #pragma unroll
    for (int i = 0; i < 16; ++i) {
        unsigned cnt = hist[tid * 16 + i];
        if (cum <= 102u && 102u < cum + cnt) { info[0] = tid * 16 + i; info[1] = (int)cum; }
        cum += cnt;
    }
    __syncthreads();
    const int Bstar = info[0];
    const int L = info[1];
    const int need = K_SEL - L;

    for (int v = tid; v < 2048; v += 256) {
        unsigned bb = ebits[v];
        float e = __uint_as_float(bb);
        int bin = (int)(e * 8192.0f); bin = (bin > 4095) ? 4095 : bin;
        if (bin < Bstar) {
            int s2 = atomicAdd(&counters[0], 1);
            sel_v[s2] = v; sel_e[s2] = e;
        } else if (bin == Bstar) {
            int s2 = atomicAdd(&counters[1], 1);
            if (s2 < 128) bnd[s2] = (((ull_t)bb) << 32) | (unsigned)v;
        }
    }
    __syncthreads();
    if (tid == 0) {
        int nb = counters[1]; if (nb > 128) nb = 128;
        for (int i = 1; i < nb; ++i) {
            ull_t key = bnd[i]; int j2 = i - 1;
            while (j2 >= 0 && bnd[j2] > key) { bnd[j2 + 1] = bnd[j2]; --j2; }
            bnd[j2 + 1] = key;
        }
        for (int i = 0; i < need; ++i) {
            sel_v[L + i] = (int)(unsigned)(bnd[i] & 0xffffffffull);
            sel_e[L + i] = __uint_as_float((unsigned)(bnd[i] >> 32));
        }
        emax_s = __uint_as_float((unsigned)(bnd[need - 1] >> 32));
    }
    __syncthreads();

    const float denom = (emax_s - e_min) + 1e-8f;
    float w = 0.0f;
    if (tid < K_SEL) w = __expf(-(sel_e[tid] - e_min) / denom);
    if (tid < K_SEL) sel_e[tid] = w;
    if (tid < 128) sred[tid] = (tid < K_SEL) ? w : 0.0f;
    __syncthreads();
    for (int s = 64; s > 0; s >>= 1) {
        if (tid < s) sred[tid] += sred[tid + s];
        __syncthreads();
    }
    const float total = sred[0];

    // ---- MLP: 2 threads per k -> Hs[j][k] (LDS), then coalesced store
    if (tid < 2 * K_SEL) {
        const int k = tid >> 1;
        const int io = (tid & 1) * 16;
        const int v = sel_v[k];
        const float kd = sel_e[k] / total;
        float d0 = qp0 - pos[v * 2 + 0];
        float d1 = qp1 - pos[v * 2 + 1];
        d0 += 0.5f; d0 -= floorf(d0); d0 -= 0.5f;
        d1 += 0.5f; d1 -= floorf(d1); d1 -= 0.5f;
        float kf[32];
        #pragma unroll
        for (int f = 0; f < 16; ++f) {
            float t = d0 * Bm[f] + d1 * Bm[16 + f];   // revolutions
            float r = t - rintf(t);
            kf[f]      = __builtin_amdgcn_sinf(r);
            kf[16 + f] = __builtin_amdgcn_cosf(r);
        }
        #pragma unroll 4
        for (int i = io; i < io + 16; ++i) {
            float pre = b1s[i];
            #pragma unroll
            for (int jf = 0; jf < 32; ++jf) pre += kf[jf] * W1s[i * 32 + jf];
            float g = 0.5f * pre * (1.0f + erff(pre * 0.70710678118654752f));
            Hs[i * 128 + k] = (_Float16)(g * kd);
        }
        if (io == 0) {
            Hs[32 * 128 + k] = (_Float16)kd;
            indg[q * K_SEL + k] = sel_v[k];
        }
    }
    __syncthreads();
    {   // coalesced Hh store: 48*128 halfs = 768 x half8
        _Float16* hq = Hh + (size_t)q * 6144;
        for (int t = tid; t < 768; t += 256)
            *(f16x8*)(hq + t * 8) = *(const f16x8*)(&Hs[t * 8]);
    }
}

// ---------------- K3: MFMA GEMM1 + GEMM2, block = (q, bt-pair) --------------
// XgT swizzled layout: element (c,k) at c*136 + 8*(c>>3) + k halfs
//   -> transpose-writes ~2-way banks, b128 reads 16B-aligned & bank-uniform.
// Gather covers k in [0,128) with ind duplicated (Hh zero for k>=103 masks).
__global__ __launch_bounds__(256, 3) void k3_main(const _Float16* __restrict__ xlh,
                                                  const _Float16* __restrict__ Hh,
                                                  const int* __restrict__ indg,
                                                  const _Float16* __restrict__ W2th,
                                                  const float* __restrict__ bias,
                                                  float* __restrict__ out) {
    const int bid = blockIdx.x;
    const int q = bid >> 2;
    const int bt0 = (bid & 3) * 2;
    const int tid = threadIdx.x;
    const int lane = tid & 63;
    const int wv = tid >> 6;
    const int n0 = lane & 15;
    const int quad = lane >> 4;

    __shared__ __align__(16) _Float16 Xg[2][8768];   // 35 KB swizzled
    __shared__ __align__(16) _Float16 Zh[2][2112];   // 8.4 KB
    __shared__ float red[4][2][2][16];
    __shared__ int ind_s[128];

    // ---- prefetch all GEMM1 A-fragments (independent of LDS phases)
    const _Float16* hq = Hh + (size_t)q * 6144;
    f16x8 afr[4][3];
    #pragma unroll
    for (int ks = 0; ks < 4; ++ks)
        #pragma unroll
        for (int r = 0; r < 3; ++r)
            afr[ks][r] = *(const f16x8*)(hq + (r * 16 + n0) * 128 + ks * 32 + quad * 8);

    if (tid < 128) {
        int kk = (tid < K_SEL) ? tid : tid - K_SEL;
        ind_s[tid] = indg[q * K_SEL + kk];
    }
    __syncthreads();

    // ---- gather + swizzled transpose (8 iters, coalesced 16B reads)
    for (int t = tid; t < 2048; t += 256) {
        int bt = t >> 10;
        int r = t & 1023;
        int k = r >> 3;
        int oct = r & 7;
        const _Float16* src = xlh + ((size_t)(bt0 + bt) * 2048 + ind_s[k]) * 64 + oct * 8;
        f16x8 v = *(const f16x8*)src;
        int base = oct * 1096 + k;          // oct*(8*136+8) + k
        #pragma unroll
        for (int i = 0; i < 8; ++i) Xg[bt][base + 136 * i] = v[i];
    }
    __syncthreads();

    // ---- GEMM1: wave wv covers n-tiles {2wv, 2wv+1}, 3 row-tiles
    f32x4 Dz[3][2];
    #pragma unroll
    for (int r = 0; r < 3; ++r)
        #pragma unroll
        for (int c = 0; c < 2; ++c) Dz[r][c] = (f32x4){0.f, 0.f, 0.f, 0.f};

    #pragma unroll
    for (int ks = 0; ks < 4; ++ks) {
        const int kbase = ks * 32 + quad * 8;
        #pragma unroll
        for (int ctl = 0; ctl < 2; ++ctl) {
            const int ct = wv * 2 + ctl;
            const int bt = ct >> 2;
            const int c = (ct & 3) * 16 + n0;
            f16x8 bfr = *(const f16x8*)(&Xg[bt][c * 136 + ((c >> 3) << 3) + kbase]);
            #pragma unroll
            for (int r = 0; r < 3; ++r)
                Dz[r][ctl] = __builtin_amdgcn_mfma_f32_16x16x32_f16(afr[ks][r], bfr, Dz[r][ctl], 0, 0, 0);
        }
    }
    // write Z tiles -> Zh[bt][e], e = j*64+c (C-layout row=quad*4+reg, col=n0)
    #pragma unroll
    for (int ctl = 0; ctl < 2; ++ctl) {
        const int ct = wv * 2 + ctl;
        const int bt = ct >> 2;
        const int c = (ct & 3) * 16 + n0;
        #pragma unroll
        for (int r = 0; r < 3; ++r)
            #pragma unroll
            for (int reg = 0; reg < 4; ++reg) {
                int j = r * 16 + quad * 4 + reg;
                if (j < 33) Zh[bt][j * 64 + c] = (_Float16)Dz[r][ctl][reg];
            }
    }
    __syncthreads();

    // ---- GEMM2: steps s = wv, wv+4, ... (66 steps of K=32)
    f32x4 D2[2];
    D2[0] = (f32x4){0.f, 0.f, 0.f, 0.f};
    D2[1] = (f32x4){0.f, 0.f, 0.f, 0.f};
    for (int s = wv; s < 66; s += 4) {
        const int e0 = s * 32 + quad * 8;
        f16x8 afr2 = {0, 0, 0, 0, 0, 0, 0, 0};
        if (n0 < 2) afr2 = *(const f16x8*)(&Zh[n0][e0]);
        #pragma unroll
        for (int dt = 0; dt < 2; ++dt) {
            f16x8 bfr = *(const f16x8*)(W2th + (size_t)(dt * 16 + n0) * 2112 + e0);
            D2[dt] = __builtin_amdgcn_mfma_f32_16x16x32_f16(afr2, bfr, D2[dt], 0, 0, 0);
        }
    }
    if (quad == 0) {
        red[wv][0][0][n0] = D2[0][0];
        red[wv][0][1][n0] = D2[0][1];
        red[wv][1][0][n0] = D2[1][0];
        red[wv][1][1][n0] = D2[1][1];
    }
    __syncthreads();
    if (tid < 64) {
        const int bt = tid >> 5;
        const int d = tid & 31;
        const int dt = d >> 4;
        const int dn = d & 15;
        float s = bias[d];
        #pragma unroll
        for (int w2 = 0; w2 < 4; ++w2) s += red[w2][dt][bt][dn];
        out[((size_t)(bt0 + bt) * 512 + q) * 32 + d] = s;
    }
}

// ---------------------------------------------------------------------------
extern "C" void kernel_launch(void* const* d_in, const int* in_sizes, int n_in,
                              void* d_out, int out_size, void* d_ws, size_t ws_size,
                              hipStream_t stream) {
    const float* x     = (const float*)d_in[0];   // (2,4,2048,64)
    const float* pos   = (const float*)d_in[1];   // (2048,2)
    const float* qpos  = (const float*)d_in[2];   // (512,2)
    const float* W_lin = (const float*)d_in[3];   // (64,64)
    const float* b_lin = (const float*)d_in[4];   // (64)
    const float* Bmat  = (const float*)d_in[5];   // (2,16)
    const float* W1    = (const float*)d_in[6];   // (32,32)
    const float* b1    = (const float*)d_in[7];   // (32)
    const float* W2    = (const float*)d_in[8];   // (2048,32)
    const float* filt  = (const float*)d_in[9];   // (2048)
    const float* bias  = (const float*)d_in[10];  // (32)
    float* out = (float*)d_out;

    float* ws = (float*)d_ws;
    _Float16* xlh  = (_Float16*)ws;                 // 1048576 halfs
    _Float16* Hh   = (_Float16*)(ws + 524288);      // 512*48*128 halfs
    int*      indg = (int*)(ws + 2097152);          // 52736 ints
    _Float16* W2th = (_Float16*)(ws + 2150144);     // 32*2112 halfs

    k1_lin<<<1024, 256, 0, stream>>>(x, W_lin, b_lin, xlh, W2, filt, W2th);
    k2_select<<<512, 256, 0, stream>>>(pos, qpos, Bmat, W1, b1, Hh, indg);
    k3_main<<<2048, 256, 0, stream>>>(xlh, Hh, indg, W2th, bias, out);
}

// Round 7
// 148.354 us; speedup vs baseline: 1.5099x; 1.0956x over previous
//
#include <hip/hip_runtime.h>

#define K_SEL 103
typedef unsigned long long ull_t;
typedef _Float16 f16x8 __attribute__((ext_vector_type(8)));
typedef float f32x4 __attribute__((ext_vector_type(4)));

// ================= K12: fused (k2 select+MLP | k1 lin+W2th) =================
// blocks [0,512): per-query selection + MLP -> Hh (A-layout, UNNORMALIZED by
//   softmax total; invtot[q] applied in k3 epilogue), indg, invtot.
// blocks [512,1536): xlh = fp16(x @ W_lin^T + b_lin) (16 rows each) + W2th.
__global__ __launch_bounds__(256) void k12(const float* __restrict__ pos,
                                           const float* __restrict__ qpos,
                                           const float* __restrict__ Bmat,
                                           const float* __restrict__ W1,
                                           const float* __restrict__ b1,
                                           _Float16* __restrict__ Hh,
                                           int* __restrict__ indg,
                                           float* __restrict__ invtot,
                                           const float* __restrict__ x,
                                           const float* __restrict__ W,
                                           const float* __restrict__ b,
                                           _Float16* __restrict__ xlh,
                                           const float* __restrict__ W2,
                                           const float* __restrict__ filt,
                                           _Float16* __restrict__ W2th) {
    __shared__ __align__(16) unsigned char smem[43136];
    const int tid = threadIdx.x;

    if (blockIdx.x >= 512) {
        // ------------------------- k1 path --------------------------------
        const int bb = blockIdx.x - 512;
        float* Wt = (float*)smem;                      // 64x64
        if (tid < 66) {
            int t = bb * 66 + tid;
            int d = t & 31;
            int e = t >> 5;
            int c = e & 63;
            int j = e >> 6;
            float v = (j < 32) ? W2[(c * 32 + d) * 32 + j] : filt[c * 32 + d];
            W2th[d * 2112 + e] = (_Float16)v;
        }
        for (int t = tid; t < 4096; t += 256)
            Wt[(t & 63) * 64 + (t >> 6)] = W[t];
        __syncthreads();
        int i = tid & 63;
        int sub = tid >> 6;
        int r0 = bb * 16 + sub * 4;
        float bi = b[i];
        float acc0 = bi, acc1 = bi, acc2 = bi, acc3 = bi;
        const float* xr = x + (size_t)r0 * 64;
        #pragma unroll 4
        for (int jj = 0; jj < 16; ++jj) {
            float4 v0 = *(const float4*)(xr + 0 * 64 + jj * 4);
            float4 v1 = *(const float4*)(xr + 1 * 64 + jj * 4);
            float4 v2 = *(const float4*)(xr + 2 * 64 + jj * 4);
            float4 v3 = *(const float4*)(xr + 3 * 64 + jj * 4);
            float w0 = Wt[(jj * 4 + 0) * 64 + i];
            float w1 = Wt[(jj * 4 + 1) * 64 + i];
            float w2 = Wt[(jj * 4 + 2) * 64 + i];
            float w3 = Wt[(jj * 4 + 3) * 64 + i];
            acc0 += v0.x * w0 + v0.y * w1 + v0.z * w2 + v0.w * w3;
            acc1 += v1.x * w0 + v1.y * w1 + v1.z * w2 + v1.w * w3;
            acc2 += v2.x * w0 + v2.y * w1 + v2.z * w2 + v2.w * w3;
            acc3 += v3.x * w0 + v3.y * w1 + v3.z * w2 + v3.w * w3;
        }
        xlh[(size_t)(r0 + 0) * 64 + i] = (_Float16)acc0;
        xlh[(size_t)(r0 + 1) * 64 + i] = (_Float16)acc1;
        xlh[(size_t)(r0 + 2) * 64 + i] = (_Float16)acc2;
        xlh[(size_t)(r0 + 3) * 64 + i] = (_Float16)acc3;
        return;
    }

    // --------------------------- k2 path ---------------------------------
    const int q = blockIdx.x;
    const int lane = tid & 63;
    const int wid = tid >> 6;

    unsigned* ebits   = (unsigned*)(smem + 0);        // [2048]
    unsigned* hist    = (unsigned*)(smem + 8192);     // [4096]
    float*    W1s     = (float*)(smem + 24576);       // [1024]
    _Float16* Hs      = (_Float16*)(smem + 28672);    // [6144]
    float*    b1s     = (float*)(smem + 40960);       // [32]
    float*    Bm      = (float*)(smem + 41088);       // [32]
    int*      sel_v   = (int*)(smem + 41216);         // [104]
    float*    sel_e   = (float*)(smem + 41632);       // [104]
    ull_t*    bnd     = (ull_t*)(smem + 42048);       // [128]
    int*      counters= (int*)(smem + 43072);         // [2]
    int*      info    = (int*)(smem + 43080);         // [2]
    float*    wred    = (float*)(smem + 43088);       // [4]
    float*    emax_s  = (float*)(smem + 43104);       // [1]
    unsigned* wscan   = (unsigned*)(smem + 43108);    // [4]

    for (int t = tid; t < 1024; t += 256) W1s[t] = W1[t];
    if (tid < 32) { b1s[tid] = b1[tid]; Bm[tid] = Bmat[tid]; }
    if (tid < 2)  counters[tid] = 0;
    for (int t = tid; t < 1024; t += 256) ((uint4*)hist)[t] = make_uint4(0, 0, 0, 0);
    {   f16x8 z = {0, 0, 0, 0, 0, 0, 0, 0};
        for (int t = tid; t < 768; t += 256) ((f16x8*)Hs)[t] = z;
    }
    const float qp0 = qpos[q * 2 + 0];
    const float qp1 = qpos[q * 2 + 1];
    __syncthreads();

    float lmin = 1e30f;
    for (int v = tid; v < 2048; v += 256) {
        float2 p = ((const float2*)pos)[v];
        float d0 = qp0 - p.x;
        float d1 = qp1 - p.y;
        d0 += 0.5f; d0 -= floorf(d0); d0 -= 0.5f;
        d1 += 0.5f; d1 -= floorf(d1); d1 -= 0.5f;
        float e = d0 * d0 + d1 * d1;
        ebits[v] = __float_as_uint(e);
        lmin = fminf(lmin, e);
        int bb = (int)(e * 8192.0f); bb = (bb > 4095) ? 4095 : bb;
        atomicAdd(&hist[bb], 1u);
    }
    #pragma unroll
    for (int off = 32; off > 0; off >>= 1)
        lmin = fminf(lmin, __shfl_xor(lmin, off, 64));
    if (lane == 0) wred[wid] = lmin;
    __syncthreads();            // hist complete + wred ready
    const float e_min = fminf(fminf(wred[0], wred[1]), fminf(wred[2], wred[3]));

    // ---- scan of 4096-bin histogram
    unsigned lsum = 0;
    #pragma unroll
    for (int i = 0; i < 16; ++i) lsum += hist[tid * 16 + i];
    unsigned vq = lsum;
    #pragma unroll
    for (int off = 1; off < 64; off <<= 1) {
        unsigned n = __shfl_up(vq, off, 64);
        if (lane >= off) vq += n;
    }
    if (lane == 63) wscan[wid] = vq;
    __syncthreads();
    unsigned base = 0;
    for (int w2 = 0; w2 < wid; ++w2) base += wscan[w2];
    unsigned cum = base + vq - lsum;
    #pragma unroll
    for (int i = 0; i < 16; ++i) {
        unsigned cnt = hist[tid * 16 + i];
        if (cum <= 102u && 102u < cum + cnt) { info[0] = tid * 16 + i; info[1] = (int)cum; }
        cum += cnt;
    }
    __syncthreads();
    const int Bstar = info[0];
    const int L = info[1];
    const int need = K_SEL - L;

    for (int v = tid; v < 2048; v += 256) {
        unsigned bb = ebits[v];
        float e = __uint_as_float(bb);
        int bin = (int)(e * 8192.0f); bin = (bin > 4095) ? 4095 : bin;
        if (bin < Bstar) {
            int s2 = atomicAdd(&counters[0], 1);
            sel_v[s2] = v; sel_e[s2] = e;
        } else if (bin == Bstar) {
            int s2 = atomicAdd(&counters[1], 1);
            if (s2 < 128) bnd[s2] = (((ull_t)bb) << 32) | (unsigned)v;
        }
    }
    __syncthreads();
    if (tid == 0) {
        int nb = counters[1]; if (nb > 128) nb = 128;
        for (int i = 1; i < nb; ++i) {
            ull_t key = bnd[i]; int j2 = i - 1;
            while (j2 >= 0 && bnd[j2] > key) { bnd[j2 + 1] = bnd[j2]; --j2; }
            bnd[j2 + 1] = key;
        }
        for (int i = 0; i < need; ++i) {
            sel_v[L + i] = (int)(unsigned)(bnd[i] & 0xffffffffull);
            sel_e[L + i] = __uint_as_float((unsigned)(bnd[i] >> 32));
        }
        emax_s[0] = __uint_as_float((unsigned)(bnd[need - 1] >> 32));
    }
    __syncthreads();

    const float denom = (emax_s[0] - e_min) + 1e-8f;
    float w = 0.0f;
    if (tid < K_SEL) {
        w = __expf(-(sel_e[tid] - e_min) / denom);
        sel_e[tid] = w;           // own-slot overwrite: e no longer needed
    }
    __syncthreads();

    // ---- MLP with UNNORMALIZED w (invtot applied in k3)
    if (tid < 2 * K_SEL) {
        const int k = tid >> 1;
        const int io = (tid & 1) * 16;
        const int v = sel_v[k];
        const float wk = sel_e[k];
        float2 p = ((const float2*)pos)[v];
        float d0 = qp0 - p.x;
        float d1 = qp1 - p.y;
        d0 += 0.5f; d0 -= floorf(d0); d0 -= 0.5f;
        d1 += 0.5f; d1 -= floorf(d1); d1 -= 0.5f;
        float kf[32];
        #pragma unroll
        for (int f = 0; f < 16; ++f) {
            float t = d0 * Bm[f] + d1 * Bm[16 + f];   // revolutions
            float r = t - rintf(t);
            kf[f]      = __builtin_amdgcn_sinf(r);
            kf[16 + f] = __builtin_amdgcn_cosf(r);
        }
        #pragma unroll 4
        for (int i = io; i < io + 16; ++i) {
            float pre = b1s[i];
            #pragma unroll
            for (int jf = 0; jf < 32; ++jf) pre += kf[jf] * W1s[i * 32 + jf];
            float g = 0.5f * pre * (1.0f + erff(pre * 0.70710678118654752f));
            Hs[i * 128 + k] = (_Float16)(g * wk);
        }
        if (io == 0) {
            Hs[32 * 128 + k] = (_Float16)wk;
            indg[q * K_SEL + k] = v;
        }
    }
    __syncthreads();

    // ---- Hh store (coalesced) + total reduce -> invtot
    {
        _Float16* hq = Hh + (size_t)q * 6144;
        for (int t = tid; t < 768; t += 256)
            ((f16x8*)hq)[t] = ((const f16x8*)Hs)[t];
    }
    float sw = w;                 // 0 for tid >= 103
    #pragma unroll
    for (int off = 32; off > 0; off >>= 1)
        sw += __shfl_xor(sw, off, 64);
    if (lane == 0) wred[wid] = sw;
    __syncthreads();
    if (tid == 0)
        invtot[q] = 1.0f / (wred[0] + wred[1] + wred[2] + wred[3]);
}

// ---------------- K3: MFMA GEMM1 + GEMM2, block = (q, bt-pair) --------------
// Xg swizzled: element (bt,c,k) at bt*8768 + c*136 + 8*(c>>3) + k halfs.
// Zh aliases Xg (extra barrier). GEMM2 uses dual accumulator chains.
__global__ __launch_bounds__(256, 4) void k3_main(const _Float16* __restrict__ xlh,
                                                  const _Float16* __restrict__ Hh,
                                                  const int* __restrict__ indg,
                                                  const _Float16* __restrict__ W2th,
                                                  const float* __restrict__ bias,
                                                  const float* __restrict__ invtot,
                                                  float* __restrict__ out) {
    const int bid = blockIdx.x;
    const int q = bid >> 2;
    const int bt0 = (bid & 3) * 2;
    const int tid = threadIdx.x;
    const int lane = tid & 63;
    const int wv = tid >> 6;
    const int n0 = lane & 15;
    const int quad = lane >> 4;

    __shared__ __align__(16) _Float16 Xg[17536];     // 35072 B (2 x 8768)
    __shared__ float red[4][2][2][16];               // 1024 B
    __shared__ int ind_s[128];
    _Float16* Zh = &Xg[0];                           // alias (after barrier)

    // ---- prefetch GEMM1 A-fragments + invtot
    const _Float16* hq = Hh + (size_t)q * 6144;
    f16x8 afr[4][3];
    #pragma unroll
    for (int ks = 0; ks < 4; ++ks)
        #pragma unroll
        for (int r = 0; r < 3; ++r)
            afr[ks][r] = *(const f16x8*)(hq + (r * 16 + n0) * 128 + ks * 32 + quad * 8);
    const float it = invtot[q];

    if (tid < 128) {
        int kk = (tid < K_SEL) ? tid : tid - K_SEL;
        ind_s[tid] = indg[q * K_SEL + kk];
    }
    __syncthreads();

    // ---- gather + swizzled transpose, 2 batches of 4 in-flight loads
    #pragma unroll
    for (int half = 0; half < 2; ++half) {
        f16x8 v[4];
        int base[4];
        #pragma unroll
        for (int i = 0; i < 4; ++i) {
            int t = tid + (half * 4 + i) * 256;
            int bt = t >> 10;
            int r = t & 1023;
            int k = r >> 3;
            int oct = r & 7;
            v[i] = *(const f16x8*)(xlh + ((size_t)(bt0 + bt) * 2048 + ind_s[k]) * 64 + oct * 8);
            base[i] = bt * 8768 + oct * 1096 + k;
        }
        #pragma unroll
        for (int i = 0; i < 4; ++i)
            #pragma unroll
            for (int jj = 0; jj < 8; ++jj)
                Xg[base[i] + 136 * jj] = v[i][jj];
    }
    __syncthreads();

    // ---- GEMM1
    f32x4 Dz[3][2];
    #pragma unroll
    for (int r = 0; r < 3; ++r)
        #pragma unroll
        for (int c = 0; c < 2; ++c) Dz[r][c] = (f32x4){0.f, 0.f, 0.f, 0.f};

    #pragma unroll
    for (int ks = 0; ks < 4; ++ks) {
        const int kbase = ks * 32 + quad * 8;
        #pragma unroll
        for (int ctl = 0; ctl < 2; ++ctl) {
            const int ct = wv * 2 + ctl;
            const int bt = ct >> 2;
            const int c = (ct & 3) * 16 + n0;
            f16x8 bfr = *(const f16x8*)(&Xg[bt * 8768 + c * 136 + ((c >> 3) << 3) + kbase]);
            #pragma unroll
            for (int r = 0; r < 3; ++r)
                Dz[r][ctl] = __builtin_amdgcn_mfma_f32_16x16x32_f16(afr[ks][r], bfr, Dz[r][ctl], 0, 0, 0);
        }
    }
    __syncthreads();    // all Xg reads done -> safe to write aliased Zh

    #pragma unroll
    for (int ctl = 0; ctl < 2; ++ctl) {
        const int ct = wv * 2 + ctl;
        const int bt = ct >> 2;
        const int c = (ct & 3) * 16 + n0;
        #pragma unroll
        for (int r = 0; r < 3; ++r)
            #pragma unroll
            for (int reg = 0; reg < 4; ++reg) {
                int j = r * 16 + quad * 4 + reg;
                if (j < 33) Zh[bt * 2112 + j * 64 + c] = (_Float16)Dz[r][ctl][reg];
            }
    }
    __syncthreads();

    // ---- GEMM2: dual accumulator chains over s = wv, wv+4, ...
    f32x4 D2[2][2];
    #pragma unroll
    for (int p = 0; p < 2; ++p)
        #pragma unroll
        for (int dt = 0; dt < 2; ++dt) D2[p][dt] = (f32x4){0.f, 0.f, 0.f, 0.f};
    int p = 0;
    #pragma unroll 2
    for (int s = wv; s < 66; s += 4) {
        const int e0 = s * 32 + quad * 8;
        f16x8 afr2 = {0, 0, 0, 0, 0, 0, 0, 0};
        if (n0 < 2) afr2 = *(const f16x8*)(&Zh[n0 * 2112 + e0]);
        #pragma unroll
        for (int dt = 0; dt < 2; ++dt) {
            f16x8 bfr = *(const f16x8*)(W2th + (size_t)(dt * 16 + n0) * 2112 + e0);
            D2[p][dt] = __builtin_amdgcn_mfma_f32_16x16x32_f16(afr2, bfr, D2[p][dt], 0, 0, 0);
        }
        p ^= 1;
    }
    #pragma unroll
    for (int dt = 0; dt < 2; ++dt)
        D2[0][dt] = D2[0][dt] + D2[1][dt];

    if (quad == 0) {
        red[wv][0][0][n0] = D2[0][0][0];
        red[wv][0][1][n0] = D2[0][0][1];
        red[wv][1][0][n0] = D2[0][1][0];
        red[wv][1][1][n0] = D2[0][1][1];
    }
    __syncthreads();
    if (tid < 64) {
        const int bt = tid >> 5;
        const int d = tid & 31;
        const int dt = d >> 4;
        const int dn = d & 15;
        float s = 0.0f;
        #pragma unroll
        for (int w2 = 0; w2 < 4; ++w2) s += red[w2][dt][bt][dn];
        out[((size_t)(bt0 + bt) * 512 + q) * 32 + d] = bias[d] + it * s;
    }
}

// ---------------------------------------------------------------------------
extern "C" void kernel_launch(void* const* d_in, const int* in_sizes, int n_in,
                              void* d_out, int out_size, void* d_ws, size_t ws_size,
                              hipStream_t stream) {
    const float* x     = (const float*)d_in[0];   // (2,4,2048,64)
    const float* pos   = (const float*)d_in[1];   // (2048,2)
    const float* qpos  = (const float*)d_in[2];   // (512,2)
    const float* W_lin = (const float*)d_in[3];   // (64,64)
    const float* b_lin = (const float*)d_in[4];   // (64)
    const float* Bmat  = (const float*)d_in[5];   // (2,16)
    const float* W1    = (const float*)d_in[6];   // (32,32)
    const float* b1    = (const float*)d_in[7];   // (32)
    const float* W2    = (const float*)d_in[8];   // (2048,32)
    const float* filt  = (const float*)d_in[9];   // (2048)
    const float* bias  = (const float*)d_in[10];  // (32)
    float* out = (float*)d_out;

    float* ws = (float*)d_ws;
    _Float16* xlh    = (_Float16*)ws;               // 1048576 halfs
    _Float16* Hh     = (_Float16*)(ws + 524288);    // 512*6144 halfs
    int*      indg   = (int*)(ws + 2097152);        // 52736 ints
    _Float16* W2th   = (_Float16*)(ws + 2150144);   // 32*2112 halfs
    float*    invtot = ws + 2183936;                // 512 floats

    k12<<<1536, 256, 0, stream>>>(pos, qpos, Bmat, W1, b1, Hh, indg, invtot,
                                  x, W_lin, b_lin, xlh, W2, filt, W2th);
    k3_main<<<2048, 256, 0, stream>>>(xlh, Hh, indg, W2th, bias, invtot, out);
}

// Round 9
// 133.978 us; speedup vs baseline: 1.6720x; 1.1073x over previous
//
#include <hip/hip_runtime.h>

#define K_SEL 103
typedef unsigned long long ull_t;
typedef _Float16 f16x8 __attribute__((ext_vector_type(8)));
typedef float f32x4 __attribute__((ext_vector_type(4)));

// ================= K12: fused (k2 select+MLP | k1 lin+W2th) =================
// grid 1024: blocks [0,512) = per-query select+MLP -> Hh (A-layout,
// unnormalized; invtot applied in k3), indg, invtot.
// blocks [512,1024) = xlh = fp16(x @ W_lin^T + b) (32 rows each) + W2th chunk.
__global__ __launch_bounds__(256, 4) void k12(const float* __restrict__ pos,
                                              const float* __restrict__ qpos,
                                              const float* __restrict__ Bmat,
                                              const float* __restrict__ W1,
                                              const float* __restrict__ b1,
                                              _Float16* __restrict__ Hh,
                                              int* __restrict__ indg,
                                              float* __restrict__ invtot,
                                              const float* __restrict__ x,
                                              const float* __restrict__ W,
                                              const float* __restrict__ b,
                                              _Float16* __restrict__ xlh,
                                              const float* __restrict__ W2,
                                              const float* __restrict__ filt,
                                              _Float16* __restrict__ W2th) {
    __shared__ __align__(16) unsigned char smem[30848];
    const int tid = threadIdx.x;
    const int bid = blockIdx.x;
    const int lane = tid & 63;
    const int wid = tid >> 6;

    if (bid >= 512) {
        // ---------------- k1 path: 32 rows + W2th chunk --------------------
        const int bb = bid - 512;
        float* Wt = (float*)smem;                  // 64x64 = 16 KB
        if (tid < 132) {
            int t = bb * 132 + tid;                // 512*132 = 67584 exactly
            int d = t & 31;
            int e = t >> 5;
            int c = e & 63;
            int j = e >> 6;
            float v = (j < 32) ? W2[(c * 32 + d) * 32 + j] : filt[c * 32 + d];
            W2th[d * 2112 + e] = (_Float16)v;
        }
        for (int t = tid; t < 4096; t += 256)
            Wt[(t & 63) * 64 + (t >> 6)] = W[t];
        __syncthreads();
        const int i = tid & 63;
        const int sub = tid >> 6;
        const float bi = b[i];
        #pragma unroll
        for (int rr = 0; rr < 2; ++rr) {
            const int r0 = bb * 32 + rr * 16 + sub * 4;
            float acc0 = bi, acc1 = bi, acc2 = bi, acc3 = bi;
            const float* xr = x + (size_t)r0 * 64;
            #pragma unroll 4
            for (int jj = 0; jj < 16; ++jj) {
                float4 v0 = *(const float4*)(xr + 0 * 64 + jj * 4);
                float4 v1 = *(const float4*)(xr + 1 * 64 + jj * 4);
                float4 v2 = *(const float4*)(xr + 2 * 64 + jj * 4);
                float4 v3 = *(const float4*)(xr + 3 * 64 + jj * 4);
                float w0 = Wt[(jj * 4 + 0) * 64 + i];
                float w1 = Wt[(jj * 4 + 1) * 64 + i];
                float w2 = Wt[(jj * 4 + 2) * 64 + i];
                float w3 = Wt[(jj * 4 + 3) * 64 + i];
                acc0 += v0.x * w0 + v0.y * w1 + v0.z * w2 + v0.w * w3;
                acc1 += v1.x * w0 + v1.y * w1 + v1.z * w2 + v1.w * w3;
                acc2 += v2.x * w0 + v2.y * w1 + v2.z * w2 + v2.w * w3;
                acc3 += v3.x * w0 + v3.y * w1 + v3.z * w2 + v3.w * w3;
            }
            xlh[(size_t)(r0 + 0) * 64 + i] = (_Float16)acc0;
            xlh[(size_t)(r0 + 1) * 64 + i] = (_Float16)acc1;
            xlh[(size_t)(r0 + 2) * 64 + i] = (_Float16)acc2;
            xlh[(size_t)(r0 + 3) * 64 + i] = (_Float16)acc3;
        }
        return;
    }

    // ---------------- k2 path: select + MLP --------------------------------
    const int q = bid;
    unsigned* ebits   = (unsigned*)(smem);            // 8192 B
    unsigned* hist    = (unsigned*)(smem + 8192);     // 16384 B
    _Float16* Hs      = (_Float16*)(smem + 8192);     // 12288 B (alias hist)
    float*    W1s     = (float*)(smem + 24576);       // 4096 B
    float*    b1s     = (float*)(smem + 28672);
    float*    Bm      = (float*)(smem + 28800);
    int*      sel_v   = (int*)(smem + 28928);         // 104
    float*    sel_e   = (float*)(smem + 29344);       // 104
    ull_t*    bnd     = (ull_t*)(smem + 29760);       // 128
    int*      counters= (int*)(smem + 30784);
    int*      info    = (int*)(smem + 30792);
    float*    wred    = (float*)(smem + 30800);       // 4
    float*    emax_s  = (float*)(smem + 30816);
    unsigned* wscan   = (unsigned*)(smem + 30824);    // 4

    for (int t = tid; t < 1024; t += 256) W1s[t] = W1[t];
    if (tid < 32) { b1s[tid] = b1[tid]; Bm[tid] = Bmat[tid]; }
    if (tid < 2)  counters[tid] = 0;
    for (int t = tid; t < 1024; t += 256) ((uint4*)hist)[t] = make_uint4(0, 0, 0, 0);
    const float qp0 = qpos[q * 2 + 0];
    const float qp1 = qpos[q * 2 + 1];
    __syncthreads();

    float lmin = 1e30f;
    for (int v = tid; v < 2048; v += 256) {
        float2 p = ((const float2*)pos)[v];
        float d0 = qp0 - p.x;
        float d1 = qp1 - p.y;
        d0 += 0.5f; d0 -= floorf(d0); d0 -= 0.5f;
        d1 += 0.5f; d1 -= floorf(d1); d1 -= 0.5f;
        float e = d0 * d0 + d1 * d1;
        ebits[v] = __float_as_uint(e);
        lmin = fminf(lmin, e);
        int bb2 = (int)(e * 8192.0f); bb2 = (bb2 > 4095) ? 4095 : bb2;
        atomicAdd(&hist[bb2], 1u);
    }
    #pragma unroll
    for (int off = 32; off > 0; off >>= 1)
        lmin = fminf(lmin, __shfl_xor(lmin, off, 64));
    if (lane == 0) wred[wid] = lmin;
    __syncthreads();
    const float e_min = fminf(fminf(wred[0], wred[1]), fminf(wred[2], wred[3]));

    unsigned lsum = 0;
    #pragma unroll
    for (int i = 0; i < 16; ++i) lsum += hist[tid * 16 + i];
    unsigned vq = lsum;
    #pragma unroll
    for (int off = 1; off < 64; off <<= 1) {
        unsigned n = __shfl_up(vq, off, 64);
        if (lane >= off) vq += n;
    }
    if (lane == 63) wscan[wid] = vq;
    __syncthreads();
    unsigned base = 0;
    for (int w2 = 0; w2 < wid; ++w2) base += wscan[w2];
    unsigned cum = base + vq - lsum;
    #pragma unroll
    for (int i = 0; i < 16; ++i) {
        unsigned cnt = hist[tid * 16 + i];
        if (cum <= 102u && 102u < cum + cnt) { info[0] = tid * 16 + i; info[1] = (int)cum; }
        cum += cnt;
    }
    __syncthreads();          // all hist reads done -> hist dead
    const int Bstar = info[0];
    const int L = info[1];
    const int need = K_SEL - L;

    // compaction + zero Hs (aliases dead hist; sel/bnd live outside)
    {
        f16x8 z = {0, 0, 0, 0, 0, 0, 0, 0};
        for (int t = tid; t < 768; t += 256) ((f16x8*)Hs)[t] = z;
    }
    for (int v = tid; v < 2048; v += 256) {
        unsigned bb2 = ebits[v];
        float e = __uint_as_float(bb2);
        int bin = (int)(e * 8192.0f); bin = (bin > 4095) ? 4095 : bin;
        if (bin < Bstar) {
            int s2 = atomicAdd(&counters[0], 1);
            sel_v[s2] = v; sel_e[s2] = e;
        } else if (bin == Bstar) {
            int s2 = atomicAdd(&counters[1], 1);
            if (s2 < 128) bnd[s2] = (((ull_t)bb2) << 32) | (unsigned)v;
        }
    }
    __syncthreads();
    if (tid == 0) {
        int nb = counters[1]; if (nb > 128) nb = 128;
        for (int i = 1; i < nb; ++i) {
            ull_t key = bnd[i]; int j2 = i - 1;
            while (j2 >= 0 && bnd[j2] > key) { bnd[j2 + 1] = bnd[j2]; --j2; }
            bnd[j2 + 1] = key;
        }
        for (int i = 0; i < need; ++i) {
            sel_v[L + i] = (int)(unsigned)(bnd[i] & 0xffffffffull);
            sel_e[L + i] = __uint_as_float((unsigned)(bnd[i] >> 32));
        }
        emax_s[0] = __uint_as_float((unsigned)(bnd[need - 1] >> 32));
    }
    __syncthreads();

    const float denom = (emax_s[0] - e_min) + 1e-8f;
    float w = 0.0f;
    if (tid < K_SEL) {
        w = __expf(-(sel_e[tid] - e_min) / denom);
        sel_e[tid] = w;
    }
    float sw = w;
    #pragma unroll
    for (int off = 32; off > 0; off >>= 1)
        sw += __shfl_xor(sw, off, 64);
    if (lane == 0) wred[wid] = sw;
    __syncthreads();
    if (tid == 0)
        invtot[q] = 1.0f / (wred[0] + wred[1] + wred[2] + wred[3]);

    // MLP with unnormalized w: 2 threads per k
    if (tid < 2 * K_SEL) {
        const int k = tid >> 1;
        const int io = (tid & 1) * 16;
        const int v = sel_v[k];
        const float wk = sel_e[k];
        float2 p = ((const float2*)pos)[v];
        float d0 = qp0 - p.x;
        float d1 = qp1 - p.y;
        d0 += 0.5f; d0 -= floorf(d0); d0 -= 0.5f;
        d1 += 0.5f; d1 -= floorf(d1); d1 -= 0.5f;
        float kf[32];
        #pragma unroll
        for (int f = 0; f < 16; ++f) {
            float t = d0 * Bm[f] + d1 * Bm[16 + f];   // revolutions
            float r = t - rintf(t);
            kf[f]      = __builtin_amdgcn_sinf(r);
            kf[16 + f] = __builtin_amdgcn_cosf(r);
        }
        #pragma unroll 4
        for (int i = io; i < io + 16; ++i) {
            float pre = b1s[i];
            #pragma unroll
            for (int jf = 0; jf < 32; ++jf) pre += kf[jf] * W1s[i * 32 + jf];
            float g = 0.5f * pre * (1.0f + erff(pre * 0.70710678118654752f));
            Hs[i * 128 + k] = (_Float16)(g * wk);
        }
        if (io == 0) {
            Hs[32 * 128 + k] = (_Float16)wk;
            indg[q * K_SEL + k] = v;
        }
    }
    __syncthreads();
    {
        _Float16* hq = Hh + (size_t)q * 6144;
        for (int t = tid; t < 768; t += 256)
            ((f16x8*)hq)[t] = ((const f16x8*)Hs)[t];
    }
}

// ---------------- K3: MFMA GEMM1+GEMM2, block = (q, bt-half), 2 passes ------
// Setup (afr, ind_s, invtot) loaded once; pass-B gather loads issued before
// pass-A GEMM1 so their latency hides under pass-A compute.
__global__ __launch_bounds__(256, 4) void k3_main(const _Float16* __restrict__ xlh,
                                                  const _Float16* __restrict__ Hh,
                                                  const int* __restrict__ indg,
                                                  const _Float16* __restrict__ W2th,
                                                  const float* __restrict__ bias,
                                                  const float* __restrict__ invtot,
                                                  float* __restrict__ out) {
    const int bid = blockIdx.x;
    const int q = bid >> 1;
    const int tid = threadIdx.x;
    const int lane = tid & 63;
    const int wv = tid >> 6;
    const int n0 = lane & 15;
    const int quad = lane >> 4;

    __shared__ __align__(16) unsigned char smem[36608];
    _Float16* Xg = (_Float16*)smem;                 // 17536 halfs (swizzled)
    _Float16* Zh = Xg;                              // alias (barrier-guarded)
    float* red = (float*)(smem + 35072);            // 1024 B
    int* ind_s = (int*)(smem + 36096);              // 128 ints

    // ---- setup (once for both passes)
    const _Float16* hq = Hh + (size_t)q * 6144;
    f16x8 afr[4][3];
    #pragma unroll
    for (int ks = 0; ks < 4; ++ks)
        #pragma unroll
        for (int r = 0; r < 3; ++r)
            afr[ks][r] = *(const f16x8*)(hq + (r * 16 + n0) * 128 + ks * 32 + quad * 8);
    const float it = invtot[q];
    if (tid < 128) {
        int kk = (tid < K_SEL) ? tid : tid - K_SEL;
        ind_s[tid] = indg[q * K_SEL + kk];
    }
    __syncthreads();

    // decompose gather slot once: t = tid + i*256
    int g_bt[8], g_k[8], g_oct[8];
    #pragma unroll
    for (int i = 0; i < 8; ++i) {
        int t = tid + i * 256;
        g_bt[i] = t >> 10;
        int r = t & 1023;
        g_k[i] = r >> 3;
        g_oct[i] = r & 7;
    }
    const int bt0A = (bid & 1) * 4;
    const int bt0B = bt0A + 2;

    // ---- pass A gather loads + LDS write
    {
        f16x8 v[8];
        #pragma unroll
        for (int i = 0; i < 8; ++i)
            v[i] = *(const f16x8*)(xlh + ((size_t)(bt0A + g_bt[i]) * 2048 + ind_s[g_k[i]]) * 64 + g_oct[i] * 8);
        #pragma unroll
        for (int i = 0; i < 8; ++i) {
            int base = g_bt[i] * 8768 + g_oct[i] * 1096 + g_k[i];
            #pragma unroll
            for (int jj = 0; jj < 8; ++jj) Xg[base + 136 * jj] = v[i][jj];
        }
    }
    __syncthreads();

    // ---- issue pass-B gather loads (in flight during pass-A compute)
    f16x8 vB[8];
    #pragma unroll
    for (int i = 0; i < 8; ++i)
        vB[i] = *(const f16x8*)(xlh + ((size_t)(bt0B + g_bt[i]) * 2048 + ind_s[g_k[i]]) * 64 + g_oct[i] * 8);

    #pragma unroll
    for (int pass = 0; pass < 2; ++pass) {
        const int bt0 = pass ? bt0B : bt0A;
        if (pass) {
            // write prefetched pass-B data (Zh reads of pass A already fenced)
            #pragma unroll
            for (int i = 0; i < 8; ++i) {
                int base = g_bt[i] * 8768 + g_oct[i] * 1096 + g_k[i];
                #pragma unroll
                for (int jj = 0; jj < 8; ++jj) Xg[base + 136 * jj] = vB[i][jj];
            }
            __syncthreads();
        }

        // ---- GEMM1
        f32x4 Dz[3][2];
        #pragma unroll
        for (int r = 0; r < 3; ++r)
            #pragma unroll
            for (int c = 0; c < 2; ++c) Dz[r][c] = (f32x4){0.f, 0.f, 0.f, 0.f};
        #pragma unroll
        for (int ks = 0; ks < 4; ++ks) {
            const int kbase = ks * 32 + quad * 8;
            #pragma unroll
            for (int ctl = 0; ctl < 2; ++ctl) {
                const int ct = wv * 2 + ctl;
                const int bt = ct >> 2;
                const int c = (ct & 3) * 16 + n0;
                f16x8 bfr = *(const f16x8*)(&Xg[bt * 8768 + c * 136 + ((c >> 3) << 3) + kbase]);
                #pragma unroll
                for (int r = 0; r < 3; ++r)
                    Dz[r][ctl] = __builtin_amdgcn_mfma_f32_16x16x32_f16(afr[ks][r], bfr, Dz[r][ctl], 0, 0, 0);
            }
        }
        __syncthreads();    // Xg reads done -> safe to write aliased Zh

        #pragma unroll
        for (int ctl = 0; ctl < 2; ++ctl) {
            const int ct = wv * 2 + ctl;
            const int bt = ct >> 2;
            const int c = (ct & 3) * 16 + n0;
            #pragma unroll
            for (int r = 0; r < 3; ++r)
                #pragma unroll
                for (int reg = 0; reg < 4; ++reg) {
                    int j = r * 16 + quad * 4 + reg;
                    if (j < 33) Zh[bt * 2112 + j * 64 + c] = (_Float16)Dz[r][ctl][reg];
                }
        }
        __syncthreads();

        // ---- GEMM2: dual accumulator chains
        f32x4 D2[2][2];
        #pragma unroll
        for (int p = 0; p < 2; ++p)
            #pragma unroll
            for (int dt = 0; dt < 2; ++dt) D2[p][dt] = (f32x4){0.f, 0.f, 0.f, 0.f};
        int p = 0;
        #pragma unroll 2
        for (int s = wv; s < 66; s += 4) {
            const int e0 = s * 32 + quad * 8;
            f16x8 afr2 = {0, 0, 0, 0, 0, 0, 0, 0};
            if (n0 < 2) afr2 = *(const f16x8*)(&Zh[n0 * 2112 + e0]);
            #pragma unroll
            for (int dt = 0; dt < 2; ++dt) {
                f16x8 bfr = *(const f16x8*)(W2th + (size_t)(dt * 16 + n0) * 2112 + e0);
                D2[p][dt] = __builtin_amdgcn_mfma_f32_16x16x32_f16(afr2, bfr, D2[p][dt], 0, 0, 0);
            }
            p ^= 1;
        }
        #pragma unroll
        for (int dt = 0; dt < 2; ++dt)
            D2[0][dt] = D2[0][dt] + D2[1][dt];

        if (quad == 0) {
            red[(wv * 4 + 0) * 16 + n0] = D2[0][0][0];   // dt0 bt0
            red[(wv * 4 + 1) * 16 + n0] = D2[0][0][1];   // dt0 bt1
            red[(wv * 4 + 2) * 16 + n0] = D2[0][1][0];   // dt1 bt0
            red[(wv * 4 + 3) * 16 + n0] = D2[0][1][1];   // dt1 bt1
        }
        __syncthreads();   // red ready AND all Zh reads done
        if (tid < 64) {
            const int bt = tid >> 5;
            const int d = tid & 31;
            const int dt = d >> 4;
            const int dn = d & 15;
            float s = 0.0f;
            #pragma unroll
            for (int w2 = 0; w2 < 4; ++w2)
                s += red[(w2 * 4 + dt * 2 + bt) * 16 + dn];
            out[((size_t)(bt0 + bt) * 512 + q) * 32 + d] = bias[d] + it * s;
        }
        // pass-B Xg write may start immediately: red/Xg disjoint, and the
        // barrier above fenced all Zh(=Xg) reads of this pass.
    }
}

// ---------------------------------------------------------------------------
extern "C" void kernel_launch(void* const* d_in, const int* in_sizes, int n_in,
                              void* d_out, int out_size, void* d_ws, size_t ws_size,
                              hipStream_t stream) {
    const float* x     = (const float*)d_in[0];   // (2,4,2048,64)
    const float* pos   = (const float*)d_in[1];   // (2048,2)
    const float* qpos  = (const float*)d_in[2];   // (512,2)
    const float* W_lin = (const float*)d_in[3];   // (64,64)
    const float* b_lin = (const float*)d_in[4];   // (64)
    const float* Bmat  = (const float*)d_in[5];   // (2,16)
    const float* W1    = (const float*)d_in[6];   // (32,32)
    const float* b1    = (const float*)d_in[7];   // (32)
    const float* W2    = (const float*)d_in[8];   // (2048,32)
    const float* filt  = (const float*)d_in[9];   // (2048)
    const float* bias  = (const float*)d_in[10];  // (32)
    float* out = (float*)d_out;

    float* ws = (float*)d_ws;
    _Float16* xlh    = (_Float16*)ws;               // 1048576 halfs
    _Float16* Hh     = (_Float16*)(ws + 524288);    // 512*6144 halfs
    int*      indg   = (int*)(ws + 2097152);        // 52736 ints
    _Float16* W2th   = (_Float16*)(ws + 2150144);   // 32*2112 halfs
    float*    invtot = ws + 2183936;                // 512 floats

    k12<<<1024, 256, 0, stream>>>(pos, qpos, Bmat, W1, b1, Hh, indg, invtot,
                                  x, W_lin, b_lin, xlh, W2, filt, W2th);
    k3_main<<<1024, 256, 0, stream>>>(xlh, Hh, indg, W2th, bias, invtot, out);
}